// Round 1
// baseline (1076.638 us; speedup 1.0000x reference)
//
#include <hip/hip_runtime.h>
#include <hip/hip_bf16.h>
#include <cstddef>
#include <cstdint>

#define EPS 1e-5f

// =============== GEMM: Y[M][N] = X[M][K] @ W[N][K]^T + bias ===============
#define BMT 128
#define BNT 128
#define BKT 16

__global__ __launch_bounds__(256) void gemm_xwT_bias(
    const float* __restrict__ X, const float* __restrict__ W,
    const float* __restrict__ bias, float* __restrict__ Y,
    int M, int N, int K)
{
  __shared__ float Xs[BKT][BMT + 4];
  __shared__ float Ws[BKT][BNT + 4];
  const int tid = threadIdx.x;
  const int bm = blockIdx.y * BMT;
  const int bn = blockIdx.x * BNT;
  const int tx = tid & 15;
  const int ty = tid >> 4;

  float acc[8][8];
#pragma unroll
  for (int i = 0; i < 8; ++i)
#pragma unroll
    for (int j = 0; j < 8; ++j) acc[i][j] = 0.f;

  for (int k0 = 0; k0 < K; k0 += BKT) {
    __syncthreads();
#pragma unroll
    for (int it = 0; it < 2; ++it) {
      int qi = tid + it * 256;
      int m = qi & 127;
      int kq = qi >> 7;
      int kk = k0 + kq * 4;
      float4 xv = *reinterpret_cast<const float4*>(&X[(size_t)(bm + m) * K + kk]);
      Xs[kq * 4 + 0][m] = xv.x; Xs[kq * 4 + 1][m] = xv.y;
      Xs[kq * 4 + 2][m] = xv.z; Xs[kq * 4 + 3][m] = xv.w;
      float4 wv = *reinterpret_cast<const float4*>(&W[(size_t)(bn + m) * K + kk]);
      Ws[kq * 4 + 0][m] = wv.x; Ws[kq * 4 + 1][m] = wv.y;
      Ws[kq * 4 + 2][m] = wv.z; Ws[kq * 4 + 3][m] = wv.w;
    }
    __syncthreads();
#pragma unroll
    for (int k = 0; k < BKT; ++k) {
      float a[8], b[8];
      *reinterpret_cast<float4*>(&a[0]) = *reinterpret_cast<const float4*>(&Xs[k][ty * 8]);
      *reinterpret_cast<float4*>(&a[4]) = *reinterpret_cast<const float4*>(&Xs[k][ty * 8 + 4]);
      *reinterpret_cast<float4*>(&b[0]) = *reinterpret_cast<const float4*>(&Ws[k][tx * 8]);
      *reinterpret_cast<float4*>(&b[4]) = *reinterpret_cast<const float4*>(&Ws[k][tx * 8 + 4]);
#pragma unroll
      for (int i = 0; i < 8; ++i)
#pragma unroll
        for (int j = 0; j < 8; ++j)
          acc[i][j] = fmaf(a[i], b[j], acc[i][j]);
    }
  }
#pragma unroll
  for (int i = 0; i < 8; ++i) {
    int m = bm + ty * 8 + i;
    int n0 = bn + tx * 8;
    float4 o0, o1;
    o0.x = acc[i][0] + bias[n0 + 0];
    o0.y = acc[i][1] + bias[n0 + 1];
    o0.z = acc[i][2] + bias[n0 + 2];
    o0.w = acc[i][3] + bias[n0 + 3];
    o1.x = acc[i][4] + bias[n0 + 4];
    o1.y = acc[i][5] + bias[n0 + 5];
    o1.z = acc[i][6] + bias[n0 + 6];
    o1.w = acc[i][7] + bias[n0 + 7];
    *reinterpret_cast<float4*>(&Y[(size_t)m * N + n0]) = o0;
    *reinterpret_cast<float4*>(&Y[(size_t)m * N + n0 + 4]) = o1;
  }
}

// =============== BatchNorm stats: deterministic two-stage fp64 ===============
__global__ void bn_stats(const float* __restrict__ Y, double* __restrict__ psum,
                         double* __restrict__ psq, int M, int N, int rowsPerBlk)
{
  int c = blockIdx.x * blockDim.x + threadIdx.x;
  int r0 = blockIdx.y * rowsPerBlk;
  double s = 0.0, q = 0.0;
  for (int r = r0; r < r0 + rowsPerBlk; ++r) {
    float v = Y[(size_t)r * N + c];
    s += (double)v;
    q += (double)v * (double)v;
  }
  psum[(size_t)blockIdx.y * N + c] = s;
  psq[(size_t)blockIdx.y * N + c] = q;
}

__global__ void bn_finalize(const double* __restrict__ psum, const double* __restrict__ psq,
                            const float* __restrict__ g,
                            float* __restrict__ meanv, float* __restrict__ Av,
                            int N, int RB, double invM)
{
  int c = blockIdx.x * blockDim.x + threadIdx.x;
  double s = 0.0, q = 0.0;
  for (int rb = 0; rb < RB; ++rb) {
    s += psum[(size_t)rb * N + c];
    q += psq[(size_t)rb * N + c];
  }
  double m = s * invM;
  double var = q * invM - m * m;
  if (var < 0.0) var = 0.0;
  meanv[c] = (float)m;
  Av[c] = g[c] * rsqrtf((float)var + EPS);
}

// spike( bn(Y) ) elementwise: out = ((Y-m)*A + beta >= thresh) ? 1 : 0
__global__ void bn_spike(const float* __restrict__ Y, const float* __restrict__ meanv,
                         const float* __restrict__ Av, const float* __restrict__ beta,
                         float* __restrict__ S, int N, float thresh)
{
  size_t idx4 = (size_t)blockIdx.x * blockDim.x + threadIdx.x;
  size_t base = idx4 * 4;
  int c0 = (int)(base & (size_t)(N - 1));
  float4 y = *reinterpret_cast<const float4*>(&Y[base]);
  float4 o;
  o.x = ((y.x - meanv[c0 + 0]) * Av[c0 + 0] + beta[c0 + 0] >= thresh) ? 1.f : 0.f;
  o.y = ((y.y - meanv[c0 + 1]) * Av[c0 + 1] + beta[c0 + 1] >= thresh) ? 1.f : 0.f;
  o.z = ((y.z - meanv[c0 + 2]) * Av[c0 + 2] + beta[c0 + 2] >= thresh) ? 1.f : 0.f;
  o.w = ((y.w - meanv[c0 + 3]) * Av[c0 + 3] + beta[c0 + 3] >= thresh) ? 1.f : 0.f;
  *reinterpret_cast<float4*>(&S[base]) = o;
}

// =============== energy[b,h] = mean_n sum_{d in head} q*k ===============
__global__ void energy_kernel(const float* __restrict__ qb, const float* __restrict__ kb,
                              float* __restrict__ energy, int Ntok, int D, int hd)
{
  int bh = blockIdx.x;
  int b = bh >> 4, h = bh & 15;
  const float* qp = qb + (size_t)b * Ntok * D + h * hd;
  const float* kp = kb + (size_t)b * Ntok * D + h * hd;
  int tid = threadIdx.x;
  float s = 0.f;
  for (int idx = tid; idx < Ntok * hd; idx += blockDim.x) {
    int n = idx >> 6;           // hd = 64
    int dd = idx & 63;
    s += qp[(size_t)n * D + dd] * kp[(size_t)n * D + dd];
  }
  __shared__ float red[256];
  red[tid] = s;
  __syncthreads();
  for (int off = 128; off; off >>= 1) {
    if (tid < off) red[tid] += red[tid + off];
    __syncthreads();
  }
  if (tid == 0) energy[bh] = red[0] / (float)Ntok;
}

// =============== gate[b,h'] = (sum_j energy[b, j%16]*Wg[h',j] + bg >= 0.5) ===============
__global__ void gate_kernel(const float* __restrict__ energy, const float* __restrict__ Wg,
                            const float* __restrict__ bg, float* __restrict__ gate,
                            int B, int H, int D)
{
  int t = threadIdx.x;
  if (t < B * H) {
    int b = t / H, hp = t % H;
    float e[16];
    for (int h = 0; h < 16; ++h) e[h] = energy[b * 16 + h];
    float pre = 0.f;
    for (int j = 0; j < D; ++j) pre = fmaf(e[j & 15], Wg[(size_t)hp * D + j], pre);
    pre += bg[hp];
    gate[t] = (pre >= 0.5f) ? 1.f : 0.f;
  }
}

// =============== gated attention + spike (early-out when gate==0) ===============
__global__ __launch_bounds__(256) void attn_kernel(
    const float* __restrict__ qb, const float* __restrict__ kb, const float* __restrict__ vb,
    const float* __restrict__ gate, float* __restrict__ xs,
    int Ntok, int D, float scale)
{
  int bh = blockIdx.x;
  int b = bh >> 4, h = bh & 15;
  int n0 = blockIdx.y * 32;
  int tid = threadIdx.x;
  float* outbase = xs + (size_t)(b * Ntok + n0) * D + h * 64;

  if (gate[bh] == 0.f) {
    // x_attn for this head is exactly zero -> spike(0 >= 1.0) = 0
    for (int i = tid; i < 32 * 16; i += 256) {
      int r = i >> 4, c4 = (i & 15) << 2;
      *reinterpret_cast<float4*>(&outbase[(size_t)r * D + c4]) = make_float4(0.f, 0.f, 0.f, 0.f);
    }
    return;
  }

  __shared__ float qs[32][68], ks[32][68], vs[32][68], Ss[32][36];
  const float* qg = qb + (size_t)b * Ntok * D + h * 64;
  const float* kg = kb + (size_t)b * Ntok * D + h * 64;
  const float* vg = vb + (size_t)b * Ntok * D + h * 64;

  {
    int r = tid >> 3, c8 = (tid & 7) * 8;
    *reinterpret_cast<float4*>(&qs[r][c8]) =
        *reinterpret_cast<const float4*>(&qg[(size_t)(n0 + r) * D + c8]);
    *reinterpret_cast<float4*>(&qs[r][c8 + 4]) =
        *reinterpret_cast<const float4*>(&qg[(size_t)(n0 + r) * D + c8 + 4]);
  }

  float acc[8];
#pragma unroll
  for (int j = 0; j < 8; ++j) acc[j] = 0.f;

  const int nloc = tid >> 3;
  const int dd0 = (tid & 7) * 8;

  for (int mt = 0; mt < Ntok / 32; ++mt) {
    int m0 = mt * 32;
    __syncthreads();
    {
      int r = tid >> 3, c8 = (tid & 7) * 8;
      *reinterpret_cast<float4*>(&ks[r][c8]) =
          *reinterpret_cast<const float4*>(&kg[(size_t)(m0 + r) * D + c8]);
      *reinterpret_cast<float4*>(&ks[r][c8 + 4]) =
          *reinterpret_cast<const float4*>(&kg[(size_t)(m0 + r) * D + c8 + 4]);
      *reinterpret_cast<float4*>(&vs[r][c8]) =
          *reinterpret_cast<const float4*>(&vg[(size_t)(m0 + r) * D + c8]);
      *reinterpret_cast<float4*>(&vs[r][c8 + 4]) =
          *reinterpret_cast<const float4*>(&vg[(size_t)(m0 + r) * D + c8 + 4]);
    }
    __syncthreads();
    // S[n][m'] = sum_d q[n][d] * k[m'][d]
    {
      int np = tid >> 3;
      int mp0 = (tid & 7) * 4;
      float s0 = 0.f, s1 = 0.f, s2 = 0.f, s3 = 0.f;
#pragma unroll 8
      for (int d = 0; d < 64; ++d) {
        float qv = qs[np][d];
        s0 = fmaf(qv, ks[mp0 + 0][d], s0);
        s1 = fmaf(qv, ks[mp0 + 1][d], s1);
        s2 = fmaf(qv, ks[mp0 + 2][d], s2);
        s3 = fmaf(qv, ks[mp0 + 3][d], s3);
      }
      Ss[np][mp0 + 0] = s0; Ss[np][mp0 + 1] = s1;
      Ss[np][mp0 + 2] = s2; Ss[np][mp0 + 3] = s3;
    }
    __syncthreads();
    // acc[n][dd] += sum_m' S[n][m'] * v[m'][dd]
#pragma unroll 8
    for (int mp = 0; mp < 32; ++mp) {
      float sv = Ss[nloc][mp];
#pragma unroll
      for (int j = 0; j < 8; ++j) acc[j] = fmaf(sv, vs[mp][dd0 + j], acc[j]);
    }
  }

  // gate == 1 here: x = scale * acc ; spike(x/2 >= 0.5) <=> x >= 1.0
#pragma unroll
  for (int j = 0; j < 8; ++j) {
    float x = scale * acc[j];
    outbase[(size_t)nloc * D + dd0 + j] = (x >= 1.0f) ? 1.f : 0.f;
  }
}

// ======================================================================
extern "C" void kernel_launch(void* const* d_in, const int* in_sizes, int n_in,
                              void* d_out, int out_size, void* d_ws, size_t ws_size,
                              hipStream_t stream)
{
  (void)in_sizes; (void)n_in; (void)out_size; (void)ws_size;
  const int B = 4, Ntok = 1024, D = 1024, H = 16, hd = 64;
  const int M = B * Ntok;           // 4096 token rows
  const float scale = 0.5946035575013605f;  // 64^(-1/8)

  const float* x     = (const float*)d_in[0];
  const float* Wq    = (const float*)d_in[1];
  const float* bq    = (const float*)d_in[2];
  const float* gq    = (const float*)d_in[3];
  const float* betaq = (const float*)d_in[4];
  const float* Wk    = (const float*)d_in[5];
  const float* bk    = (const float*)d_in[6];
  const float* gk    = (const float*)d_in[7];
  const float* betak = (const float*)d_in[8];
  const float* Wv    = (const float*)d_in[9];
  const float* bv    = (const float*)d_in[10];
  const float* gv    = (const float*)d_in[11];
  const float* betav = (const float*)d_in[12];
  const float* Wp    = (const float*)d_in[13];
  const float* bp    = (const float*)d_in[14];
  const float* gp    = (const float*)d_in[15];
  const float* betap = (const float*)d_in[16];
  const float* Wg    = (const float*)d_in[17];
  const float* bg    = (const float*)d_in[18];

  char* w = (char*)d_ws;
  const size_t MB = 1024 * 1024;
  float*  Y      = (float*)(w + 0 * MB);        // 16 MB
  float*  qb2    = (float*)(w + 16 * MB);
  float*  kb2    = (float*)(w + 32 * MB);
  float*  vb2    = (float*)(w + 48 * MB);
  float*  xat    = (float*)(w + 64 * MB);
  double* psum   = (double*)(w + 80 * MB);              // 16*1024 doubles
  double* psq    = (double*)(w + 80 * MB + 131072);
  float*  meanv  = (float*)(w + 80 * MB + 262144);
  float*  Av     = (float*)(w + 80 * MB + 262144 + 4096);
  float*  energy = (float*)(w + 80 * MB + 262144 + 8192);
  float*  gate   = (float*)(w + 80 * MB + 262144 + 8448);

  const int RB = 16;
  const int rowsPerBlk = M / RB;                 // 256
  dim3 gemmGrid(D / BNT, M / BMT);               // (8, 32)
  dim3 statsGrid(D / 256, RB);
  dim3 spikeGrid((M * D) / (256 * 4));           // 4096
  float* out = (float*)d_out;

  // ---- q branch ----
  gemm_xwT_bias<<<gemmGrid, 256, 0, stream>>>(x, Wq, bq, Y, M, D, D);
  bn_stats<<<statsGrid, 256, 0, stream>>>(Y, psum, psq, M, D, rowsPerBlk);
  bn_finalize<<<dim3(D / 256), 256, 0, stream>>>(psum, psq, gq, meanv, Av, D, RB, 1.0 / M);
  bn_spike<<<spikeGrid, 256, 0, stream>>>(Y, meanv, Av, betaq, qb2, D, 2.0f);
  // ---- k branch ----
  gemm_xwT_bias<<<gemmGrid, 256, 0, stream>>>(x, Wk, bk, Y, M, D, D);
  bn_stats<<<statsGrid, 256, 0, stream>>>(Y, psum, psq, M, D, rowsPerBlk);
  bn_finalize<<<dim3(D / 256), 256, 0, stream>>>(psum, psq, gk, meanv, Av, D, RB, 1.0 / M);
  bn_spike<<<spikeGrid, 256, 0, stream>>>(Y, meanv, Av, betak, kb2, D, 2.0f);
  // ---- v branch ----
  gemm_xwT_bias<<<gemmGrid, 256, 0, stream>>>(x, Wv, bv, Y, M, D, D);
  bn_stats<<<statsGrid, 256, 0, stream>>>(Y, psum, psq, M, D, rowsPerBlk);
  bn_finalize<<<dim3(D / 256), 256, 0, stream>>>(psum, psq, gv, meanv, Av, D, RB, 1.0 / M);
  bn_spike<<<spikeGrid, 256, 0, stream>>>(Y, meanv, Av, betav, vb2, D, 2.0f);

  // ---- energy + gate ----
  energy_kernel<<<dim3(B * H), 256, 0, stream>>>(qb2, kb2, energy, Ntok, D, hd);
  gate_kernel<<<dim3(1), 64, 0, stream>>>(energy, Wg, bg, gate, B, H, D);

  // ---- gated attention + spike ----
  attn_kernel<<<dim3(B * H, Ntok / 32), 256, 0, stream>>>(qb2, kb2, vb2, gate, xat, Ntok, D, scale);

  // ---- p branch -> output ----
  gemm_xwT_bias<<<gemmGrid, 256, 0, stream>>>(xat, Wp, bp, Y, M, D, D);
  bn_stats<<<statsGrid, 256, 0, stream>>>(Y, psum, psq, M, D, rowsPerBlk);
  bn_finalize<<<dim3(D / 256), 256, 0, stream>>>(psum, psq, gp, meanv, Av, D, RB, 1.0 / M);
  bn_spike<<<spikeGrid, 256, 0, stream>>>(Y, meanv, Av, betap, out, D, 2.0f);
}

// Round 2
// 625.672 us; speedup vs baseline: 1.7208x; 1.7208x over previous
//
#include <hip/hip_runtime.h>
#include <cstddef>
#include <cstdint>

#define EPS 1e-5f

typedef __bf16 bf16x8 __attribute__((ext_vector_type(8)));
typedef float f32x4 __attribute__((ext_vector_type(4)));
typedef unsigned short u16x8 __attribute__((ext_vector_type(8)));

__device__ __forceinline__ unsigned short f2bf(float f) {
  unsigned u = __builtin_bit_cast(unsigned, f);
  unsigned r = u + 0x7FFFu + ((u >> 16) & 1u);
  return (unsigned short)(r >> 16);
}
__device__ __forceinline__ float bf2f(unsigned short h) {
  unsigned u = (unsigned)h << 16;
  return __builtin_bit_cast(float, u);
}

__device__ __forceinline__ void gl_lds16(const void* g, void* l) {
  __builtin_amdgcn_global_load_lds(
      (const __attribute__((address_space(1))) unsigned int*)g,
      (__attribute__((address_space(3))) unsigned int*)l, 16, 0, 0);
}

// =============== bf16 MFMA GEMM: Y[M][N] = A[M][Kc] @ B[N][Kc]^T + bias ===============
// 64x128 tile, BK=64, 4 waves; XOR-swizzled LDS (pre-swizzled global source).
__global__ __launch_bounds__(256) void gemm_bf16_bt(
    const unsigned short* __restrict__ A, const unsigned short* __restrict__ B,
    const float* __restrict__ bias, float* __restrict__ Y,
    int N, int Kc)
{
  __shared__ unsigned short As[64 * 64];    // 8 KB  [row][k], 16B slots XOR (row&7)
  __shared__ unsigned short Bs[128 * 64];   // 16 KB
  const int tid = threadIdx.x;
  const int bm = blockIdx.y * 64;
  const int bn = blockIdx.x * 128;

  // --- staging: per-lane global src (pre-swizzled), linear LDS dst ---
  const unsigned short* aSrc[2]; unsigned short* aDst[2];
#pragma unroll
  for (int c = 0; c < 2; ++c) {
    int S = c * 256 + tid;
    int row = S >> 3, sp = S & 7;
    int sl = sp ^ (row & 7);
    aSrc[c] = A + (size_t)(bm + row) * Kc + sl * 8;
    aDst[c] = &As[S * 8];
  }
  const unsigned short* bSrc[4]; unsigned short* bDst[4];
#pragma unroll
  for (int c = 0; c < 4; ++c) {
    int S = c * 256 + tid;
    int row = S >> 3, sp = S & 7;
    int sl = sp ^ (row & 7);
    bSrc[c] = B + (size_t)(bn + row) * Kc + sl * 8;
    bDst[c] = &Bs[S * 8];
  }

  // --- fragment read offsets (ushort units) ---
  const int lane = tid & 63;
  const int w = tid >> 6;
  const int wr = w >> 1, wc = w & 1;
  const int l15 = lane & 15, g = lane >> 4;

  int aOff[2][2], bOff[4][2];
#pragma unroll
  for (int i = 0; i < 2; ++i)
#pragma unroll
    for (int t = 0; t < 2; ++t) {
      int row = wr * 32 + i * 16 + l15;
      int sphys = (t * 4 + g) ^ (row & 7);
      aOff[i][t] = row * 64 + sphys * 8;
    }
#pragma unroll
  for (int j = 0; j < 4; ++j)
#pragma unroll
    for (int t = 0; t < 2; ++t) {
      int row = wc * 64 + j * 16 + l15;
      int sphys = (t * 4 + g) ^ (row & 7);
      bOff[j][t] = row * 64 + sphys * 8;
    }

  f32x4 acc[2][4] = {};
  const int nk = Kc >> 6;
  for (int kt = 0; kt < nk; ++kt) {
    __syncthreads();
#pragma unroll
    for (int c = 0; c < 2; ++c) { gl_lds16(aSrc[c], aDst[c]); aSrc[c] += 64; }
#pragma unroll
    for (int c = 0; c < 4; ++c) { gl_lds16(bSrc[c], bDst[c]); bSrc[c] += 64; }
    __syncthreads();
#pragma unroll
    for (int t = 0; t < 2; ++t) {
      bf16x8 af[2], bfr[4];
#pragma unroll
      for (int i = 0; i < 2; ++i) af[i] = *(const bf16x8*)&As[aOff[i][t]];
#pragma unroll
      for (int j = 0; j < 4; ++j) bfr[j] = *(const bf16x8*)&Bs[bOff[j][t]];
#pragma unroll
      for (int i = 0; i < 2; ++i)
#pragma unroll
        for (int j = 0; j < 4; ++j)
          acc[i][j] = __builtin_amdgcn_mfma_f32_16x16x32_bf16(af[i], bfr[j], acc[i][j], 0, 0, 0);
    }
  }

  // epilogue: C/D layout col=lane&15, row=(lane>>4)*4+reg
  const int r0 = bm + wr * 32 + g * 4;
#pragma unroll
  for (int j = 0; j < 4; ++j) {
    int col = bn + wc * 64 + j * 16 + l15;
    float bv = bias[col];
#pragma unroll
    for (int i = 0; i < 2; ++i)
#pragma unroll
      for (int r = 0; r < 4; ++r)
        Y[(size_t)(r0 + i * 16 + r) * N + col] = acc[i][j][r] + bv;
  }
}

// =============== fp32 -> bf16 hi/lo split kernels ===============
// X [4096][1024] -> O [4096][3072] = [hi | lo | hi]
__global__ void split_x_kernel(const float* __restrict__ X, unsigned short* __restrict__ O)
{
  size_t base = ((size_t)blockIdx.x * 256 + threadIdx.x) * 4;
  int r = (int)(base >> 10), c = (int)(base & 1023);
  float4 xv = *reinterpret_cast<const float4*>(&X[base]);
  ushort4 hi, lo;
  hi.x = f2bf(xv.x); lo.x = f2bf(xv.x - bf2f(hi.x));
  hi.y = f2bf(xv.y); lo.y = f2bf(xv.y - bf2f(hi.y));
  hi.z = f2bf(xv.z); lo.z = f2bf(xv.z - bf2f(hi.z));
  hi.w = f2bf(xv.w); lo.w = f2bf(xv.w - bf2f(hi.w));
  unsigned short* Or = O + (size_t)r * 3072;
  *reinterpret_cast<ushort4*>(&Or[c]) = hi;
  *reinterpret_cast<ushort4*>(&Or[1024 + c]) = lo;
  *reinterpret_cast<ushort4*>(&Or[2048 + c]) = hi;
}

// W [1024][1024] -> O [1024][3072] = [hi | hi | lo]
__global__ void split_w_kernel(const float* __restrict__ X, unsigned short* __restrict__ O)
{
  size_t base = ((size_t)blockIdx.x * 256 + threadIdx.x) * 4;
  int r = (int)(base >> 10), c = (int)(base & 1023);
  float4 xv = *reinterpret_cast<const float4*>(&X[base]);
  ushort4 hi, lo;
  hi.x = f2bf(xv.x); lo.x = f2bf(xv.x - bf2f(hi.x));
  hi.y = f2bf(xv.y); lo.y = f2bf(xv.y - bf2f(hi.y));
  hi.z = f2bf(xv.z); lo.z = f2bf(xv.z - bf2f(hi.z));
  hi.w = f2bf(xv.w); lo.w = f2bf(xv.w - bf2f(hi.w));
  unsigned short* Or = O + (size_t)r * 3072;
  *reinterpret_cast<ushort4*>(&Or[c]) = hi;
  *reinterpret_cast<ushort4*>(&Or[1024 + c]) = hi;
  *reinterpret_cast<ushort4*>(&Or[2048 + c]) = lo;
}

// Wp [1024][1024] -> O [1024][2048] = [hi | lo]
__global__ void split_wp_kernel(const float* __restrict__ X, unsigned short* __restrict__ O)
{
  size_t base = ((size_t)blockIdx.x * 256 + threadIdx.x) * 4;
  int r = (int)(base >> 10), c = (int)(base & 1023);
  float4 xv = *reinterpret_cast<const float4*>(&X[base]);
  ushort4 hi, lo;
  hi.x = f2bf(xv.x); lo.x = f2bf(xv.x - bf2f(hi.x));
  hi.y = f2bf(xv.y); lo.y = f2bf(xv.y - bf2f(hi.y));
  hi.z = f2bf(xv.z); lo.z = f2bf(xv.z - bf2f(hi.z));
  hi.w = f2bf(xv.w); lo.w = f2bf(xv.w - bf2f(hi.w));
  unsigned short* Or = O + (size_t)r * 2048;
  *reinterpret_cast<ushort4*>(&Or[c]) = hi;
  *reinterpret_cast<ushort4*>(&Or[1024 + c]) = lo;
}

// =============== BatchNorm stats: deterministic two-stage fp64 ===============
__global__ void bn_stats(const float* __restrict__ Y, double* __restrict__ psum,
                         double* __restrict__ psq, int M, int N, int rowsPerBlk)
{
  int c = blockIdx.x * blockDim.x + threadIdx.x;
  int r0 = blockIdx.y * rowsPerBlk;
  double s = 0.0, q = 0.0;
  for (int r = r0; r < r0 + rowsPerBlk; ++r) {
    float v = Y[(size_t)r * N + c];
    s += (double)v;
    q += (double)v * (double)v;
  }
  psum[(size_t)blockIdx.y * N + c] = s;
  psq[(size_t)blockIdx.y * N + c] = q;
}

__global__ void bn_finalize(const double* __restrict__ psum, const double* __restrict__ psq,
                            const float* __restrict__ g,
                            float* __restrict__ meanv, float* __restrict__ Av,
                            int N, int RB, double invM)
{
  int c = blockIdx.x * blockDim.x + threadIdx.x;
  double s = 0.0, q = 0.0;
  for (int rb = 0; rb < RB; ++rb) {
    s += psum[(size_t)rb * N + c];
    q += psq[(size_t)rb * N + c];
  }
  double m = s * invM;
  double var = q * invM - m * m;
  if (var < 0.0) var = 0.0;
  meanv[c] = (float)m;
  Av[c] = g[c] * rsqrtf((float)var + EPS);
}

// spike(bn(Y)) -> bf16 0/1
__global__ void bn_spike_bf16(const float* __restrict__ Y, const float* __restrict__ meanv,
                              const float* __restrict__ Av, const float* __restrict__ beta,
                              unsigned short* __restrict__ S, int N, float thresh)
{
  size_t base = ((size_t)blockIdx.x * 256 + threadIdx.x) * 4;
  int c0 = (int)(base & (size_t)(N - 1));
  float4 y = *reinterpret_cast<const float4*>(&Y[base]);
  ushort4 o;
  o.x = ((y.x - meanv[c0 + 0]) * Av[c0 + 0] + beta[c0 + 0] >= thresh) ? 0x3F80 : 0;
  o.y = ((y.y - meanv[c0 + 1]) * Av[c0 + 1] + beta[c0 + 1] >= thresh) ? 0x3F80 : 0;
  o.z = ((y.z - meanv[c0 + 2]) * Av[c0 + 2] + beta[c0 + 2] >= thresh) ? 0x3F80 : 0;
  o.w = ((y.w - meanv[c0 + 3]) * Av[c0 + 3] + beta[c0 + 3] >= thresh) ? 0x3F80 : 0;
  *reinterpret_cast<ushort4*>(&S[base]) = o;
}

// spike(bn(Y)) -> fp32 0/1 (final output)
__global__ void bn_spike_f32(const float* __restrict__ Y, const float* __restrict__ meanv,
                             const float* __restrict__ Av, const float* __restrict__ beta,
                             float* __restrict__ S, int N, float thresh)
{
  size_t base = ((size_t)blockIdx.x * 256 + threadIdx.x) * 4;
  int c0 = (int)(base & (size_t)(N - 1));
  float4 y = *reinterpret_cast<const float4*>(&Y[base]);
  float4 o;
  o.x = ((y.x - meanv[c0 + 0]) * Av[c0 + 0] + beta[c0 + 0] >= thresh) ? 1.f : 0.f;
  o.y = ((y.y - meanv[c0 + 1]) * Av[c0 + 1] + beta[c0 + 1] >= thresh) ? 1.f : 0.f;
  o.z = ((y.z - meanv[c0 + 2]) * Av[c0 + 2] + beta[c0 + 2] >= thresh) ? 1.f : 0.f;
  o.w = ((y.w - meanv[c0 + 3]) * Av[c0 + 3] + beta[c0 + 3] >= thresh) ? 1.f : 0.f;
  *reinterpret_cast<float4*>(&S[base]) = o;
}

// =============== energy[b,h] = (popcount of q&k over head) / Ntok ===============
__global__ void energy_kernel(const unsigned short* __restrict__ qb,
                              const unsigned short* __restrict__ kb,
                              float* __restrict__ energy, int Ntok, int D)
{
  int bh = blockIdx.x;
  int b = bh >> 4, h = bh & 15;
  const unsigned short* qp = qb + (size_t)b * Ntok * D + h * 64;
  const unsigned short* kp = kb + (size_t)b * Ntok * D + h * 64;
  int tid = threadIdx.x;
  int cnt = 0;
  int tot = Ntok * 8;  // 8 chunks of 8 per row
  for (int idx = tid; idx < tot; idx += 256) {
    int n = idx >> 3, c8 = (idx & 7) * 8;
    u16x8 q = *reinterpret_cast<const u16x8*>(&qp[(size_t)n * D + c8]);
    u16x8 k = *reinterpret_cast<const u16x8*>(&kp[(size_t)n * D + c8]);
#pragma unroll
    for (int e = 0; e < 8; ++e) cnt += (int)((q[e] & k[e]) >> 7) & 1;
  }
  __shared__ int red[256];
  red[tid] = cnt;
  __syncthreads();
  for (int off = 128; off; off >>= 1) {
    if (tid < off) red[tid] += red[tid + off];
    __syncthreads();
  }
  if (tid == 0) energy[bh] = (float)red[0] / (float)Ntok;
}

// =============== gate[b,h'] = (sum_j energy[b, j%16]*Wg[h',j] + bg >= 0.5) ===============
__global__ void gate_kernel(const float* __restrict__ energy, const float* __restrict__ Wg,
                            const float* __restrict__ bg, float* __restrict__ gate,
                            int B, int H, int D)
{
  int t = threadIdx.x;
  if (t < B * H) {
    int b = t / H, hp = t % H;
    float e[16];
    for (int h = 0; h < 16; ++h) e[h] = energy[b * 16 + h];
    float pre = 0.f;
    for (int j = 0; j < D; ++j) pre = fmaf(e[j & 15], Wg[(size_t)hp * D + j], pre);
    pre += bg[hp];
    gate[t] = (pre >= 0.5f) ? 1.f : 0.f;
  }
}

// =============== gated attention + spike -> xat2 bf16 [4096][2048] = [s|s] ===============
__global__ __launch_bounds__(256) void attn_kernel(
    const unsigned short* __restrict__ qb, const unsigned short* __restrict__ kb,
    const unsigned short* __restrict__ vb, const float* __restrict__ gate,
    unsigned short* __restrict__ xs, int Ntok, int D, float scale)
{
  int bh = blockIdx.x;
  int b = bh >> 4, h = bh & 15;
  int n0 = blockIdx.y * 32;
  int tid = threadIdx.x;
  unsigned short* outbase = xs + (size_t)(b * Ntok + n0) * 2048 + h * 64;

  if (gate[bh] == 0.f) {
    ushort4 z = {0, 0, 0, 0};
    for (int i = tid; i < 32 * 16; i += 256) {
      int r = i >> 4, c4 = (i & 15) << 2;
      *reinterpret_cast<ushort4*>(&outbase[(size_t)r * 2048 + c4]) = z;
      *reinterpret_cast<ushort4*>(&outbase[(size_t)r * 2048 + 1024 + c4]) = z;
    }
    return;
  }

  __shared__ float qs[32][68], ks[32][68], vs[32][68], Ss[32][36];
  const unsigned short* qg = qb + (size_t)b * Ntok * D + h * 64;
  const unsigned short* kg = kb + (size_t)b * Ntok * D + h * 64;
  const unsigned short* vg = vb + (size_t)b * Ntok * D + h * 64;

  {
    int r = tid >> 3, c8 = (tid & 7) * 8;
    u16x8 t = *reinterpret_cast<const u16x8*>(&qg[(size_t)(n0 + r) * D + c8]);
#pragma unroll
    for (int e = 0; e < 8; ++e) qs[r][c8 + e] = bf2f(t[e]);
  }

  float acc[8];
#pragma unroll
  for (int j = 0; j < 8; ++j) acc[j] = 0.f;

  const int nloc = tid >> 3;
  const int dd0 = (tid & 7) * 8;

  for (int mt = 0; mt < Ntok / 32; ++mt) {
    int m0 = mt * 32;
    __syncthreads();
    {
      int r = tid >> 3, c8 = (tid & 7) * 8;
      u16x8 tk = *reinterpret_cast<const u16x8*>(&kg[(size_t)(m0 + r) * D + c8]);
      u16x8 tv = *reinterpret_cast<const u16x8*>(&vg[(size_t)(m0 + r) * D + c8]);
#pragma unroll
      for (int e = 0; e < 8; ++e) { ks[r][c8 + e] = bf2f(tk[e]); vs[r][c8 + e] = bf2f(tv[e]); }
    }
    __syncthreads();
    {
      int np = tid >> 3;
      int mp0 = (tid & 7) * 4;
      float s0 = 0.f, s1 = 0.f, s2 = 0.f, s3 = 0.f;
#pragma unroll 8
      for (int d = 0; d < 64; ++d) {
        float qv = qs[np][d];
        s0 = fmaf(qv, ks[mp0 + 0][d], s0);
        s1 = fmaf(qv, ks[mp0 + 1][d], s1);
        s2 = fmaf(qv, ks[mp0 + 2][d], s2);
        s3 = fmaf(qv, ks[mp0 + 3][d], s3);
      }
      Ss[np][mp0 + 0] = s0; Ss[np][mp0 + 1] = s1;
      Ss[np][mp0 + 2] = s2; Ss[np][mp0 + 3] = s3;
    }
    __syncthreads();
#pragma unroll 8
    for (int mp = 0; mp < 32; ++mp) {
      float sv = Ss[nloc][mp];
#pragma unroll
      for (int j = 0; j < 8; ++j) acc[j] = fmaf(sv, vs[mp][dd0 + j], acc[j]);
    }
  }

#pragma unroll
  for (int j = 0; j < 8; ++j) {
    float x = scale * acc[j];
    unsigned short sp = (x >= 1.0f) ? 0x3F80 : 0;
    outbase[(size_t)nloc * 2048 + dd0 + j] = sp;
    outbase[(size_t)nloc * 2048 + 1024 + dd0 + j] = sp;
  }
}

// ======================================================================
extern "C" void kernel_launch(void* const* d_in, const int* in_sizes, int n_in,
                              void* d_out, int out_size, void* d_ws, size_t ws_size,
                              hipStream_t stream)
{
  (void)in_sizes; (void)n_in; (void)out_size; (void)ws_size;
  const int B = 4, Ntok = 1024, D = 1024, H = 16;
  const int M = B * Ntok;                       // 4096
  const float scale = 0.5946035575013605f;      // 64^(-1/8)

  const float* x     = (const float*)d_in[0];
  const float* Wq    = (const float*)d_in[1];
  const float* bq    = (const float*)d_in[2];
  const float* gq    = (const float*)d_in[3];
  const float* betaq = (const float*)d_in[4];
  const float* Wk    = (const float*)d_in[5];
  const float* bk    = (const float*)d_in[6];
  const float* gk    = (const float*)d_in[7];
  const float* betak = (const float*)d_in[8];
  const float* Wv    = (const float*)d_in[9];
  const float* bv    = (const float*)d_in[10];
  const float* gv    = (const float*)d_in[11];
  const float* betav = (const float*)d_in[12];
  const float* Wp    = (const float*)d_in[13];
  const float* bp    = (const float*)d_in[14];
  const float* gp    = (const float*)d_in[15];
  const float* betap = (const float*)d_in[16];
  const float* Wg    = (const float*)d_in[17];
  const float* bg    = (const float*)d_in[18];

  char* w = (char*)d_ws;
  const size_t MB = 1024 * 1024;
  float*          Y     = (float*)(w + 0 * MB);            // 16 MB
  unsigned short* Xcat  = (unsigned short*)(w + 16 * MB);  // 24 MB [4096][3072]
  unsigned short* xat2  = (unsigned short*)(w + 16 * MB);  // 16 MB alias (Xcat dead by then)
  unsigned short* Wcat  = (unsigned short*)(w + 40 * MB);  // 6 MB [1024][3072] (reused; also Wp2)
  unsigned short* qb2   = (unsigned short*)(w + 46 * MB);  // 8 MB
  unsigned short* kb2   = (unsigned short*)(w + 54 * MB);  // 8 MB
  unsigned short* vb2   = (unsigned short*)(w + 62 * MB);  // 8 MB
  double* psum   = (double*)(w + 70 * MB);                 // 128 KB
  double* psq    = (double*)(w + 70 * MB + 131072);        // 128 KB
  float*  meanv  = (float*)(w + 70 * MB + 262144);
  float*  Av     = (float*)(w + 70 * MB + 262144 + 4096);
  float*  energy = (float*)(w + 70 * MB + 262144 + 8192);
  float*  gate   = (float*)(w + 70 * MB + 262144 + 8448);

  const int RB = 16;
  const int rowsPerBlk = M / RB;                 // 256
  dim3 gemmGrid(D / 128, M / 64);                // (8, 64) = 512 blocks
  dim3 statsGrid(D / 256, RB);
  dim3 spikeGrid((M * D) / (256 * 4));           // 4096
  dim3 splitXGrid((M * D) / (256 * 4));          // 4096
  dim3 splitWGrid((D * D) / (256 * 4));          // 1024
  float* out = (float*)d_out;

  // ---- input split (once) ----
  split_x_kernel<<<splitXGrid, 256, 0, stream>>>(x, Xcat);

  // ---- q branch ----
  split_w_kernel<<<splitWGrid, 256, 0, stream>>>(Wq, Wcat);
  gemm_bf16_bt<<<gemmGrid, 256, 0, stream>>>(Xcat, Wcat, bq, Y, D, 3072);
  bn_stats<<<statsGrid, 256, 0, stream>>>(Y, psum, psq, M, D, rowsPerBlk);
  bn_finalize<<<dim3(D / 256), 256, 0, stream>>>(psum, psq, gq, meanv, Av, D, RB, 1.0 / M);
  bn_spike_bf16<<<spikeGrid, 256, 0, stream>>>(Y, meanv, Av, betaq, qb2, D, 2.0f);
  // ---- k branch ----
  split_w_kernel<<<splitWGrid, 256, 0, stream>>>(Wk, Wcat);
  gemm_bf16_bt<<<gemmGrid, 256, 0, stream>>>(Xcat, Wcat, bk, Y, D, 3072);
  bn_stats<<<statsGrid, 256, 0, stream>>>(Y, psum, psq, M, D, rowsPerBlk);
  bn_finalize<<<dim3(D / 256), 256, 0, stream>>>(psum, psq, gk, meanv, Av, D, RB, 1.0 / M);
  bn_spike_bf16<<<spikeGrid, 256, 0, stream>>>(Y, meanv, Av, betak, kb2, D, 2.0f);
  // ---- v branch ----
  split_w_kernel<<<splitWGrid, 256, 0, stream>>>(Wv, Wcat);
  gemm_bf16_bt<<<gemmGrid, 256, 0, stream>>>(Xcat, Wcat, bv, Y, D, 3072);
  bn_stats<<<statsGrid, 256, 0, stream>>>(Y, psum, psq, M, D, rowsPerBlk);
  bn_finalize<<<dim3(D / 256), 256, 0, stream>>>(psum, psq, gv, meanv, Av, D, RB, 1.0 / M);
  bn_spike_bf16<<<spikeGrid, 256, 0, stream>>>(Y, meanv, Av, betav, vb2, D, 2.0f);

  // ---- energy + gate ----
  energy_kernel<<<dim3(B * H), 256, 0, stream>>>(qb2, kb2, energy, Ntok, D);
  gate_kernel<<<dim3(1), 64, 0, stream>>>(energy, Wg, bg, gate, B, H, D);

  // ---- gated attention + spike -> xat2 (bf16, duplicated halves) ----
  attn_kernel<<<dim3(B * H, Ntok / 32), 256, 0, stream>>>(qb2, kb2, vb2, gate, xat2, Ntok, D, scale);

  // ---- p branch -> output (A = [s|s] exact, B = [Wp_hi|Wp_lo], K=2048) ----
  split_wp_kernel<<<splitWGrid, 256, 0, stream>>>(Wp, Wcat);
  gemm_bf16_bt<<<gemmGrid, 256, 0, stream>>>(xat2, Wcat, bp, Y, D, 2048);
  bn_stats<<<statsGrid, 256, 0, stream>>>(Y, psum, psq, M, D, rowsPerBlk);
  bn_finalize<<<dim3(D / 256), 256, 0, stream>>>(psum, psq, gp, meanv, Av, D, RB, 1.0 / M);
  bn_spike_f32<<<spikeGrid, 256, 0, stream>>>(Y, meanv, Av, betap, out, D, 2.0f);
}

// Round 3
// 293.729 us; speedup vs baseline: 3.6654x; 2.1301x over previous
//
#include <hip/hip_runtime.h>
#include <cstddef>
#include <cstdint>

#define EPS 1e-5f

typedef __bf16 bf16x8 __attribute__((ext_vector_type(8)));
typedef float f32x4 __attribute__((ext_vector_type(4)));
typedef unsigned short u16x8 __attribute__((ext_vector_type(8)));

__device__ __forceinline__ unsigned short f2bf(float f) {
  unsigned u = __builtin_bit_cast(unsigned, f);
  unsigned r = u + 0x7FFFu + ((u >> 16) & 1u);
  return (unsigned short)(r >> 16);
}
__device__ __forceinline__ float bf2f(unsigned short h) {
  unsigned u = (unsigned)h << 16;
  return __builtin_bit_cast(float, u);
}

__device__ __forceinline__ void gl_lds16(const void* g, void* l) {
  __builtin_amdgcn_global_load_lds(
      (const __attribute__((address_space(1))) unsigned int*)g,
      (__attribute__((address_space(3))) unsigned int*)l, 16, 0, 0);
}

// =============== bf16 MFMA GEMM (128x128 tile, BK=64, 4 waves, z-batched) ===============
// Y[z][M][N] = A[M][Kc] @ Wz[N][Kc]^T + bias_z ; XOR-swizzled LDS via pre-swizzled source.
__global__ __launch_bounds__(256) void gemm3_bf16_bt(
    const unsigned short* __restrict__ A,
    const unsigned short* __restrict__ W0, const unsigned short* __restrict__ W1,
    const unsigned short* __restrict__ W2,
    const float* __restrict__ b0, const float* __restrict__ b1, const float* __restrict__ b2,
    float* __restrict__ Y, int M, int N, int Kc)
{
  const int z = blockIdx.z;
  const unsigned short* Bm = (z == 0) ? W0 : ((z == 1) ? W1 : W2);
  const float* bias = (z == 0) ? b0 : ((z == 1) ? b1 : b2);
  float* Yz = Y + (size_t)z * M * N;

  __shared__ unsigned short As[128 * 64];   // 16 KB
  __shared__ unsigned short Bs[128 * 64];   // 16 KB
  const int tid = threadIdx.x;
  const int bm = blockIdx.y * 128;
  const int bn = blockIdx.x * 128;

  // staging: 4 rounds each for A and B (256 threads x 16B = 64 rows/round)
  const unsigned short* aSrc[4]; unsigned short* aDst[4];
  const unsigned short* bSrc[4]; unsigned short* bDst[4];
#pragma unroll
  for (int c = 0; c < 4; ++c) {
    int S = c * 256 + tid;
    int row = S >> 3, sp = S & 7;
    int sl = sp ^ (row & 7);
    aSrc[c] = A  + (size_t)(bm + row) * Kc + sl * 8;
    aDst[c] = &As[S * 8];
    bSrc[c] = Bm + (size_t)(bn + row) * Kc + sl * 8;
    bDst[c] = &Bs[S * 8];
  }

  const int lane = tid & 63;
  const int w = tid >> 6;
  const int wr = w >> 1, wc = w & 1;       // wave tile 64x64
  const int l15 = lane & 15, g = lane >> 4;

  int aOff[4][2], bOff[4][2];
#pragma unroll
  for (int i = 0; i < 4; ++i)
#pragma unroll
    for (int t = 0; t < 2; ++t) {
      int rowA = wr * 64 + i * 16 + l15;
      aOff[i][t] = rowA * 64 + ((t * 4 + g) ^ (rowA & 7)) * 8;
      int rowB = wc * 64 + i * 16 + l15;
      bOff[i][t] = rowB * 64 + ((t * 4 + g) ^ (rowB & 7)) * 8;
    }

  f32x4 acc[4][4] = {};
  const int nk = Kc >> 6;
  for (int kt = 0; kt < nk; ++kt) {
    __syncthreads();
#pragma unroll
    for (int c = 0; c < 4; ++c) { gl_lds16(aSrc[c], aDst[c]); aSrc[c] += 64; }
#pragma unroll
    for (int c = 0; c < 4; ++c) { gl_lds16(bSrc[c], bDst[c]); bSrc[c] += 64; }
    __syncthreads();
#pragma unroll
    for (int t = 0; t < 2; ++t) {
      bf16x8 af[4], bfr[4];
#pragma unroll
      for (int i = 0; i < 4; ++i) af[i] = *(const bf16x8*)&As[aOff[i][t]];
#pragma unroll
      for (int j = 0; j < 4; ++j) bfr[j] = *(const bf16x8*)&Bs[bOff[j][t]];
#pragma unroll
      for (int i = 0; i < 4; ++i)
#pragma unroll
        for (int j = 0; j < 4; ++j)
          acc[i][j] = __builtin_amdgcn_mfma_f32_16x16x32_bf16(af[i], bfr[j], acc[i][j], 0, 0, 0);
    }
  }

  const int r0 = bm + wr * 64 + g * 4;
#pragma unroll
  for (int j = 0; j < 4; ++j) {
    int col = bn + wc * 64 + j * 16 + l15;
    float bv = bias[col];
#pragma unroll
    for (int i = 0; i < 4; ++i)
#pragma unroll
      for (int r = 0; r < 4; ++r)
        Yz[(size_t)(r0 + i * 16 + r) * N + col] = acc[i][j][r] + bv;
  }
}

// =============== converts ===============
// x [4096][1024] fp32 -> bf16 hi
__global__ void conv_x_kernel(const float* __restrict__ X, unsigned short* __restrict__ O)
{
  size_t base = ((size_t)blockIdx.x * 256 + threadIdx.x) * 4;
  float4 xv = *reinterpret_cast<const float4*>(&X[base]);
  ushort4 o;
  o.x = f2bf(xv.x); o.y = f2bf(xv.y); o.z = f2bf(xv.z); o.w = f2bf(xv.w);
  *reinterpret_cast<ushort4*>(&O[base]) = o;
}

// Wq,Wk,Wv -> Wh3 [3][1024][1024] bf16 hi
__global__ void conv_w3_kernel(const float* __restrict__ W0, const float* __restrict__ W1,
                               const float* __restrict__ W2, unsigned short* __restrict__ O)
{
  int z = blockIdx.y;
  const float* W = (z == 0) ? W0 : ((z == 1) ? W1 : W2);
  size_t base = ((size_t)blockIdx.x * 256 + threadIdx.x) * 4;
  float4 xv = *reinterpret_cast<const float4*>(&W[base]);
  ushort4 o;
  o.x = f2bf(xv.x); o.y = f2bf(xv.y); o.z = f2bf(xv.z); o.w = f2bf(xv.w);
  *reinterpret_cast<ushort4*>(&O[(size_t)z * 1024 * 1024 + base]) = o;
}

// Wp [1024][1024] -> O [1024][2048] = [hi | lo]
__global__ void split_wp_kernel(const float* __restrict__ X, unsigned short* __restrict__ O)
{
  size_t base = ((size_t)blockIdx.x * 256 + threadIdx.x) * 4;
  int r = (int)(base >> 10), c = (int)(base & 1023);
  float4 xv = *reinterpret_cast<const float4*>(&X[base]);
  ushort4 hi, lo;
  hi.x = f2bf(xv.x); lo.x = f2bf(xv.x - bf2f(hi.x));
  hi.y = f2bf(xv.y); lo.y = f2bf(xv.y - bf2f(hi.y));
  hi.z = f2bf(xv.z); lo.z = f2bf(xv.z - bf2f(hi.z));
  hi.w = f2bf(xv.w); lo.w = f2bf(xv.w - bf2f(hi.w));
  unsigned short* Or = O + (size_t)r * 2048;
  *reinterpret_cast<ushort4*>(&Or[c]) = hi;
  *reinterpret_cast<ushort4*>(&Or[1024 + c]) = lo;
}

// xat (bf16 0/1, [4096][1024]) is produced directly duplicated: see attn_kernel.

// =============== BatchNorm stats: deterministic two-stage fp64, z-batched ===============
__global__ void bn_stats(const float* __restrict__ Y, double* __restrict__ psum,
                         double* __restrict__ psq, int M, int N, int rowsPerBlk)
{
  int z = blockIdx.z;
  const float* Yz = Y + (size_t)z * M * N;
  int c = blockIdx.x * blockDim.x + threadIdx.x;
  int r0 = blockIdx.y * rowsPerBlk;
  double s = 0.0, q = 0.0;
  for (int r = r0; r < r0 + rowsPerBlk; ++r) {
    float v = Yz[(size_t)r * N + c];
    s += (double)v;
    q += (double)v * (double)v;
  }
  psum[((size_t)z * gridDim.y + blockIdx.y) * N + c] = s;
  psq [((size_t)z * gridDim.y + blockIdx.y) * N + c] = q;
}

__global__ void bn_finalize(const double* __restrict__ psum, const double* __restrict__ psq,
                            const float* __restrict__ g0, const float* __restrict__ g1,
                            const float* __restrict__ g2,
                            float* __restrict__ meanv, float* __restrict__ Av,
                            int N, int RB, double invM)
{
  int z = blockIdx.y;
  const float* g = (z == 0) ? g0 : ((z == 1) ? g1 : g2);
  int c = blockIdx.x * blockDim.x + threadIdx.x;
  double s = 0.0, q = 0.0;
  for (int rb = 0; rb < RB; ++rb) {
    s += psum[((size_t)z * RB + rb) * N + c];
    q += psq [((size_t)z * RB + rb) * N + c];
  }
  double m = s * invM;
  double var = q * invM - m * m;
  if (var < 0.0) var = 0.0;
  meanv[(size_t)z * N + c] = (float)m;
  Av[(size_t)z * N + c] = g[(size_t)c] * rsqrtf((float)var + EPS);
}

// spike(bn(Y)) -> bf16 0/1, z-batched (q/k/v)
__global__ void bn_spike3_bf16(const float* __restrict__ Y, const float* __restrict__ meanv,
                               const float* __restrict__ Av,
                               const float* __restrict__ be0, const float* __restrict__ be1,
                               const float* __restrict__ be2,
                               unsigned short* __restrict__ S0, unsigned short* __restrict__ S1,
                               unsigned short* __restrict__ S2, int MN, int N)
{
  int z = blockIdx.y;
  const float* Yz = Y + (size_t)z * MN;
  const float* beta = (z == 0) ? be0 : ((z == 1) ? be1 : be2);
  unsigned short* S = (z == 0) ? S0 : ((z == 1) ? S1 : S2);
  const float* mz = meanv + (size_t)z * N;
  const float* az = Av + (size_t)z * N;
  size_t base = ((size_t)blockIdx.x * 256 + threadIdx.x) * 4;
  int c0 = (int)(base & (size_t)(N - 1));
  float4 y = *reinterpret_cast<const float4*>(&Yz[base]);
  ushort4 o;
  o.x = ((y.x - mz[c0 + 0]) * az[c0 + 0] + beta[c0 + 0] >= 2.0f) ? 0x3F80 : 0;
  o.y = ((y.y - mz[c0 + 1]) * az[c0 + 1] + beta[c0 + 1] >= 2.0f) ? 0x3F80 : 0;
  o.z = ((y.z - mz[c0 + 2]) * az[c0 + 2] + beta[c0 + 2] >= 2.0f) ? 0x3F80 : 0;
  o.w = ((y.w - mz[c0 + 3]) * az[c0 + 3] + beta[c0 + 3] >= 2.0f) ? 0x3F80 : 0;
  *reinterpret_cast<ushort4*>(&S[base]) = o;
}

// spike(bn(Y)) -> fp32 0/1 (final output)
__global__ void bn_spike_f32(const float* __restrict__ Y, const float* __restrict__ meanv,
                             const float* __restrict__ Av, const float* __restrict__ beta,
                             float* __restrict__ S, int N)
{
  size_t base = ((size_t)blockIdx.x * 256 + threadIdx.x) * 4;
  int c0 = (int)(base & (size_t)(N - 1));
  float4 y = *reinterpret_cast<const float4*>(&Y[base]);
  float4 o;
  o.x = ((y.x - meanv[c0 + 0]) * Av[c0 + 0] + beta[c0 + 0] >= 2.0f) ? 1.f : 0.f;
  o.y = ((y.y - meanv[c0 + 1]) * Av[c0 + 1] + beta[c0 + 1] >= 2.0f) ? 1.f : 0.f;
  o.z = ((y.z - meanv[c0 + 2]) * Av[c0 + 2] + beta[c0 + 2] >= 2.0f) ? 1.f : 0.f;
  o.w = ((y.w - meanv[c0 + 3]) * Av[c0 + 3] + beta[c0 + 3] >= 2.0f) ? 1.f : 0.f;
  *reinterpret_cast<float4*>(&S[base]) = o;
}

// =============== energy[b,h] = (count of q&k both spiking over head) / Ntok ===============
__global__ void energy_kernel(const unsigned short* __restrict__ qb,
                              const unsigned short* __restrict__ kb,
                              float* __restrict__ energy, int Ntok, int D)
{
  int bh = blockIdx.x;
  int b = bh >> 4, h = bh & 15;
  const unsigned short* qp = qb + (size_t)b * Ntok * D + h * 64;
  const unsigned short* kp = kb + (size_t)b * Ntok * D + h * 64;
  int tid = threadIdx.x;
  int cnt = 0;
  int tot = Ntok * 8;
  for (int idx = tid; idx < tot; idx += 256) {
    int n = idx >> 3, c8 = (idx & 7) * 8;
    u16x8 q = *reinterpret_cast<const u16x8*>(&qp[(size_t)n * D + c8]);
    u16x8 k = *reinterpret_cast<const u16x8*>(&kp[(size_t)n * D + c8]);
#pragma unroll
    for (int e = 0; e < 8; ++e) cnt += (int)((q[e] & k[e]) >> 7) & 1;
  }
  __shared__ int red[256];
  red[tid] = cnt;
  __syncthreads();
  for (int off = 128; off; off >>= 1) {
    if (tid < off) red[tid] += red[tid + off];
    __syncthreads();
  }
  if (tid == 0) energy[bh] = (float)red[0] / (float)Ntok;
}

// =============== gate: one block per (b,h'), parallel reduction over D ===============
__global__ void gate_kernel(const float* __restrict__ energy, const float* __restrict__ Wg,
                            const float* __restrict__ bg, float* __restrict__ gate, int D)
{
  int b = blockIdx.x >> 4, hp = blockIdx.x & 15;
  int tid = threadIdx.x;
  float e[16];
#pragma unroll
  for (int h = 0; h < 16; ++h) e[h] = energy[b * 16 + h];
  float s = 0.f;
  for (int j = tid; j < D; j += 256) s = fmaf(e[j & 15], Wg[(size_t)hp * D + j], s);
  __shared__ float red[256];
  red[tid] = s;
  __syncthreads();
  for (int off = 128; off; off >>= 1) {
    if (tid < off) red[tid] += red[tid + off];
    __syncthreads();
  }
  if (tid == 0) gate[blockIdx.x] = (red[0] + bg[hp] >= 0.5f) ? 1.f : 0.f;
}

// =============== gated attention + spike -> xat2 bf16 [4096][2048] = [s|s] ===============
__global__ __launch_bounds__(256) void attn_kernel(
    const unsigned short* __restrict__ qb, const unsigned short* __restrict__ kb,
    const unsigned short* __restrict__ vb, const float* __restrict__ gate,
    unsigned short* __restrict__ xs, int Ntok, int D, float scale)
{
  int bh = blockIdx.x;
  int b = bh >> 4, h = bh & 15;
  int n0 = blockIdx.y * 32;
  int tid = threadIdx.x;
  unsigned short* outbase = xs + (size_t)(b * Ntok + n0) * 2048 + h * 64;

  if (gate[bh] == 0.f) {
    ushort4 zv = {0, 0, 0, 0};
    for (int i = tid; i < 32 * 16; i += 256) {
      int r = i >> 4, c4 = (i & 15) << 2;
      *reinterpret_cast<ushort4*>(&outbase[(size_t)r * 2048 + c4]) = zv;
      *reinterpret_cast<ushort4*>(&outbase[(size_t)r * 2048 + 1024 + c4]) = zv;
    }
    return;
  }

  __shared__ float qs[32][68], ks[32][68], vs[32][68], Ss[32][36];
  const unsigned short* qg = qb + (size_t)b * Ntok * D + h * 64;
  const unsigned short* kg = kb + (size_t)b * Ntok * D + h * 64;
  const unsigned short* vg = vb + (size_t)b * Ntok * D + h * 64;

  {
    int r = tid >> 3, c8 = (tid & 7) * 8;
    u16x8 t = *reinterpret_cast<const u16x8*>(&qg[(size_t)(n0 + r) * D + c8]);
#pragma unroll
    for (int e = 0; e < 8; ++e) qs[r][c8 + e] = bf2f(t[e]);
  }

  float acc[8];
#pragma unroll
  for (int j = 0; j < 8; ++j) acc[j] = 0.f;
  const int nloc = tid >> 3;
  const int dd0 = (tid & 7) * 8;

  for (int mt = 0; mt < Ntok / 32; ++mt) {
    int m0 = mt * 32;
    __syncthreads();
    {
      int r = tid >> 3, c8 = (tid & 7) * 8;
      u16x8 tk = *reinterpret_cast<const u16x8*>(&kg[(size_t)(m0 + r) * D + c8]);
      u16x8 tv = *reinterpret_cast<const u16x8*>(&vg[(size_t)(m0 + r) * D + c8]);
#pragma unroll
      for (int e = 0; e < 8; ++e) { ks[r][c8 + e] = bf2f(tk[e]); vs[r][c8 + e] = bf2f(tv[e]); }
    }
    __syncthreads();
    {
      int np = tid >> 3;
      int mp0 = (tid & 7) * 4;
      float s0 = 0.f, s1 = 0.f, s2 = 0.f, s3 = 0.f;
#pragma unroll 8
      for (int d = 0; d < 64; ++d) {
        float qv = qs[np][d];
        s0 = fmaf(qv, ks[mp0 + 0][d], s0);
        s1 = fmaf(qv, ks[mp0 + 1][d], s1);
        s2 = fmaf(qv, ks[mp0 + 2][d], s2);
        s3 = fmaf(qv, ks[mp0 + 3][d], s3);
      }
      Ss[np][mp0 + 0] = s0; Ss[np][mp0 + 1] = s1;
      Ss[np][mp0 + 2] = s2; Ss[np][mp0 + 3] = s3;
    }
    __syncthreads();
#pragma unroll 8
    for (int mp = 0; mp < 32; ++mp) {
      float sv = Ss[nloc][mp];
#pragma unroll
      for (int j = 0; j < 8; ++j) acc[j] = fmaf(sv, vs[mp][dd0 + j], acc[j]);
    }
  }

#pragma unroll
  for (int j = 0; j < 8; ++j) {
    float x = scale * acc[j];
    unsigned short sp = (x >= 1.0f) ? 0x3F80 : 0;
    outbase[(size_t)nloc * 2048 + dd0 + j] = sp;
    outbase[(size_t)nloc * 2048 + 1024 + dd0 + j] = sp;
  }
}

// ======================================================================
extern "C" void kernel_launch(void* const* d_in, const int* in_sizes, int n_in,
                              void* d_out, int out_size, void* d_ws, size_t ws_size,
                              hipStream_t stream)
{
  (void)in_sizes; (void)n_in; (void)out_size; (void)ws_size;
  const int B = 4, Ntok = 1024, D = 1024;
  const int M = B * Ntok;                       // 4096
  const float scale = 0.5946035575013605f;      // 64^(-1/8)

  const float* x     = (const float*)d_in[0];
  const float* Wq    = (const float*)d_in[1];
  const float* bq    = (const float*)d_in[2];
  const float* gq    = (const float*)d_in[3];
  const float* betaq = (const float*)d_in[4];
  const float* Wk    = (const float*)d_in[5];
  const float* bk    = (const float*)d_in[6];
  const float* gk    = (const float*)d_in[7];
  const float* betak = (const float*)d_in[8];
  const float* Wv    = (const float*)d_in[9];
  const float* bv    = (const float*)d_in[10];
  const float* gv    = (const float*)d_in[11];
  const float* betav = (const float*)d_in[12];
  const float* Wp    = (const float*)d_in[13];
  const float* bp    = (const float*)d_in[14];
  const float* gp    = (const float*)d_in[15];
  const float* betap = (const float*)d_in[16];
  const float* Wg    = (const float*)d_in[17];
  const float* bg    = (const float*)d_in[18];

  char* w = (char*)d_ws;
  const size_t MB = 1024 * 1024;
  // phase 1: Y3 [3][4096][1024] f32 at 0..48MB
  float*          Y3    = (float*)(w + 0 * MB);
  // phase 2 aliases (Y3 dead after bn_spike3):
  unsigned short* xat2  = (unsigned short*)(w + 0 * MB);    // 16 MB [4096][2048]
  float*          Yp    = (float*)(w + 16 * MB);            // 16 MB
  unsigned short* Wpcat = (unsigned short*)(w + 32 * MB);   // 4 MB [1024][2048]
  unsigned short* Xh    = (unsigned short*)(w + 48 * MB);   // 8 MB [4096][1024]
  unsigned short* Wh3   = (unsigned short*)(w + 56 * MB);   // 6 MB [3][1024][1024]
  unsigned short* qb2   = (unsigned short*)(w + 62 * MB);   // 8 MB
  unsigned short* kb2   = (unsigned short*)(w + 70 * MB);   // 8 MB
  unsigned short* vb2   = (unsigned short*)(w + 78 * MB);   // 8 MB
  double* psum   = (double*)(w + 86 * MB);                  // 3*16*1024*8 = 384 KB
  double* psq    = (double*)(w + 86 * MB + 524288);         // 384 KB
  float*  meanv  = (float*)(w + 87 * MB);                   // 12 KB
  float*  Av     = (float*)(w + 87 * MB + 16384);           // 12 KB
  float*  energy = (float*)(w + 87 * MB + 32768);
  float*  gate   = (float*)(w + 87 * MB + 32768 + 256);

  const int RB = 16;
  const int rowsPerBlk = M / RB;                 // 256
  float* out = (float*)d_out;

  // ---- converts ----
  conv_x_kernel<<<dim3((M * D) / 1024), 256, 0, stream>>>(x, Xh);
  conv_w3_kernel<<<dim3((D * D) / 1024, 3), 256, 0, stream>>>(Wq, Wk, Wv, Wh3);

  // ---- q/k/v batched: GEMM + BN + spike ----
  gemm3_bf16_bt<<<dim3(D / 128, M / 128, 3), 256, 0, stream>>>(
      Xh, Wh3, Wh3 + (size_t)D * D, Wh3 + 2 * (size_t)D * D, bq, bk, bv, Y3, M, D, 1024);
  bn_stats<<<dim3(D / 256, RB, 3), 256, 0, stream>>>(Y3, psum, psq, M, D, rowsPerBlk);
  bn_finalize<<<dim3(D / 256, 3), 256, 0, stream>>>(psum, psq, gq, gk, gv, meanv, Av, D, RB, 1.0 / M);
  bn_spike3_bf16<<<dim3((M * D) / 1024, 3), 256, 0, stream>>>(
      Y3, meanv, Av, betaq, betak, betav, qb2, kb2, vb2, M * D, D);

  // ---- energy + gate ----
  energy_kernel<<<dim3(64), 256, 0, stream>>>(qb2, kb2, energy, Ntok, D);
  gate_kernel<<<dim3(64), 256, 0, stream>>>(energy, Wg, bg, gate, D);

  // ---- gated attention + spike -> xat2 ([s|s] bf16) ----
  attn_kernel<<<dim3(64, Ntok / 32), 256, 0, stream>>>(qb2, kb2, vb2, gate, xat2, Ntok, D, scale);

  // ---- p branch: A=[s|s] (exact), B=[Wp_hi|Wp_lo], K=2048 ----
  split_wp_kernel<<<dim3((D * D) / 1024), 256, 0, stream>>>(Wp, Wpcat);
  gemm3_bf16_bt<<<dim3(D / 128, M / 128, 1), 256, 0, stream>>>(
      xat2, Wpcat, Wpcat, Wpcat, bp, bp, bp, Yp, M, D, 2048);
  bn_stats<<<dim3(D / 256, RB, 1), 256, 0, stream>>>(Yp, psum, psq, M, D, rowsPerBlk);
  bn_finalize<<<dim3(D / 256, 1), 256, 0, stream>>>(psum, psq, gp, gp, gp, meanv, Av, D, RB, 1.0 / M);
  bn_spike_f32<<<dim3((M * D) / 1024), 256, 0, stream>>>(Yp, meanv, Av, betap, out, D);
}

// Round 4
// 213.385 us; speedup vs baseline: 5.0455x; 1.3765x over previous
//
#include <hip/hip_runtime.h>
#include <cstddef>
#include <cstdint>

#define EPS 1e-5f

typedef __bf16 bf16x8 __attribute__((ext_vector_type(8)));
typedef float f32x4 __attribute__((ext_vector_type(4)));
typedef unsigned short u16x8 __attribute__((ext_vector_type(8)));

__device__ __forceinline__ unsigned short f2bf(float f) {
  unsigned u = __builtin_bit_cast(unsigned, f);
  unsigned r = u + 0x7FFFu + ((u >> 16) & 1u);
  return (unsigned short)(r >> 16);
}
__device__ __forceinline__ float bf2f(unsigned short h) {
  unsigned u = (unsigned)h << 16;
  return __builtin_bit_cast(float, u);
}

__device__ __forceinline__ void gl_lds16(const void* g, void* l) {
  __builtin_amdgcn_global_load_lds(
      (const __attribute__((address_space(1))) unsigned int*)g,
      (__attribute__((address_space(3))) unsigned int*)l, 16, 0, 0);
}

// =============== bf16 MFMA GEMM (128x128 tile, BK=64, 4 waves, z-batched) ===============
__global__ __launch_bounds__(256) void gemm3_bf16_bt(
    const unsigned short* __restrict__ A,
    const unsigned short* __restrict__ W0, const unsigned short* __restrict__ W1,
    const unsigned short* __restrict__ W2,
    const float* __restrict__ b0, const float* __restrict__ b1, const float* __restrict__ b2,
    float* __restrict__ Y, int M, int N, int Kc)
{
  const int z = blockIdx.z;
  const unsigned short* Bm = (z == 0) ? W0 : ((z == 1) ? W1 : W2);
  const float* bias = (z == 0) ? b0 : ((z == 1) ? b1 : b2);
  float* Yz = Y + (size_t)z * M * N;

  __shared__ unsigned short As[128 * 64];   // 16 KB
  __shared__ unsigned short Bs[128 * 64];   // 16 KB
  const int tid = threadIdx.x;
  const int bm = blockIdx.y * 128;
  const int bn = blockIdx.x * 128;

  const unsigned short* aSrc[4]; unsigned short* aDst[4];
  const unsigned short* bSrc[4]; unsigned short* bDst[4];
#pragma unroll
  for (int c = 0; c < 4; ++c) {
    int S = c * 256 + tid;
    int row = S >> 3, sp = S & 7;
    int sl = sp ^ (row & 7);
    aSrc[c] = A  + (size_t)(bm + row) * Kc + sl * 8;
    aDst[c] = &As[S * 8];
    bSrc[c] = Bm + (size_t)(bn + row) * Kc + sl * 8;
    bDst[c] = &Bs[S * 8];
  }

  const int lane = tid & 63;
  const int w = tid >> 6;
  const int wr = w >> 1, wc = w & 1;       // wave tile 64x64
  const int l15 = lane & 15, g = lane >> 4;

  int aOff[4][2], bOff[4][2];
#pragma unroll
  for (int i = 0; i < 4; ++i)
#pragma unroll
    for (int t = 0; t < 2; ++t) {
      int rowA = wr * 64 + i * 16 + l15;
      aOff[i][t] = rowA * 64 + ((t * 4 + g) ^ (rowA & 7)) * 8;
      int rowB = wc * 64 + i * 16 + l15;
      bOff[i][t] = rowB * 64 + ((t * 4 + g) ^ (rowB & 7)) * 8;
    }

  f32x4 acc[4][4] = {};
  const int nk = Kc >> 6;
  for (int kt = 0; kt < nk; ++kt) {
    __syncthreads();
#pragma unroll
    for (int c = 0; c < 4; ++c) { gl_lds16(aSrc[c], aDst[c]); aSrc[c] += 64; }
#pragma unroll
    for (int c = 0; c < 4; ++c) { gl_lds16(bSrc[c], bDst[c]); bSrc[c] += 64; }
    __syncthreads();
#pragma unroll
    for (int t = 0; t < 2; ++t) {
      bf16x8 af[4], bfr[4];
#pragma unroll
      for (int i = 0; i < 4; ++i) af[i] = *(const bf16x8*)&As[aOff[i][t]];
#pragma unroll
      for (int j = 0; j < 4; ++j) bfr[j] = *(const bf16x8*)&Bs[bOff[j][t]];
#pragma unroll
      for (int i = 0; i < 4; ++i)
#pragma unroll
        for (int j = 0; j < 4; ++j)
          acc[i][j] = __builtin_amdgcn_mfma_f32_16x16x32_bf16(af[i], bfr[j], acc[i][j], 0, 0, 0);
    }
  }

  const int r0 = bm + wr * 64 + g * 4;
#pragma unroll
  for (int j = 0; j < 4; ++j) {
    int col = bn + wc * 64 + j * 16 + l15;
    float bv = bias[col];
#pragma unroll
    for (int i = 0; i < 4; ++i)
#pragma unroll
      for (int r = 0; r < 4; ++r)
        Yz[(size_t)(r0 + i * 16 + r) * N + col] = acc[i][j][r] + bv;
  }
}

// =============== converts ===============
__global__ void conv_x_kernel(const float* __restrict__ X, unsigned short* __restrict__ O)
{
  size_t base = ((size_t)blockIdx.x * 256 + threadIdx.x) * 4;
  float4 xv = *reinterpret_cast<const float4*>(&X[base]);
  ushort4 o;
  o.x = f2bf(xv.x); o.y = f2bf(xv.y); o.z = f2bf(xv.z); o.w = f2bf(xv.w);
  *reinterpret_cast<ushort4*>(&O[base]) = o;
}

__global__ void conv_w3_kernel(const float* __restrict__ W0, const float* __restrict__ W1,
                               const float* __restrict__ W2, unsigned short* __restrict__ O)
{
  int z = blockIdx.y;
  const float* W = (z == 0) ? W0 : ((z == 1) ? W1 : W2);
  size_t base = ((size_t)blockIdx.x * 256 + threadIdx.x) * 4;
  float4 xv = *reinterpret_cast<const float4*>(&W[base]);
  ushort4 o;
  o.x = f2bf(xv.x); o.y = f2bf(xv.y); o.z = f2bf(xv.z); o.w = f2bf(xv.w);
  *reinterpret_cast<ushort4*>(&O[(size_t)z * 1024 * 1024 + base]) = o;
}

// Wp [1024][1024] -> O [1024][2048] = [hi | lo]
__global__ void split_wp_kernel(const float* __restrict__ X, unsigned short* __restrict__ O)
{
  size_t base = ((size_t)blockIdx.x * 256 + threadIdx.x) * 4;
  int r = (int)(base >> 10), c = (int)(base & 1023);
  float4 xv = *reinterpret_cast<const float4*>(&X[base]);
  ushort4 hi, lo;
  hi.x = f2bf(xv.x); lo.x = f2bf(xv.x - bf2f(hi.x));
  hi.y = f2bf(xv.y); lo.y = f2bf(xv.y - bf2f(hi.y));
  hi.z = f2bf(xv.z); lo.z = f2bf(xv.z - bf2f(hi.z));
  hi.w = f2bf(xv.w); lo.w = f2bf(xv.w - bf2f(hi.w));
  unsigned short* Or = O + (size_t)r * 2048;
  *reinterpret_cast<ushort4*>(&Or[c]) = hi;
  *reinterpret_cast<ushort4*>(&Or[1024 + c]) = lo;
}

// =============== BatchNorm stats: float4 cols, 4 indep fp64 chains, high MLP ===============
// grid (M/rowsPerBlk, z); block 256 threads covering all 1024 columns (4 each).
__global__ void bn_stats(const float* __restrict__ Y, double* __restrict__ psum,
                         double* __restrict__ psq, int M, int N, int rowsPerBlk)
{
  int z = blockIdx.y;
  const float* Yz = Y + (size_t)z * M * N;
  int c = threadIdx.x * 4;
  int r0 = blockIdx.x * rowsPerBlk;
  double s0 = 0, s1 = 0, s2 = 0, s3 = 0, q0 = 0, q1 = 0, q2 = 0, q3 = 0;
#pragma unroll 4
  for (int r = r0; r < r0 + rowsPerBlk; ++r) {
    float4 v = *reinterpret_cast<const float4*>(&Yz[(size_t)r * N + c]);
    s0 += v.x; q0 += (double)v.x * v.x;
    s1 += v.y; q1 += (double)v.y * v.y;
    s2 += v.z; q2 += (double)v.z * v.z;
    s3 += v.w; q3 += (double)v.w * v.w;
  }
  size_t o = ((size_t)z * gridDim.x + blockIdx.x) * N + c;
  psum[o + 0] = s0; psum[o + 1] = s1; psum[o + 2] = s2; psum[o + 3] = s3;
  psq [o + 0] = q0; psq [o + 1] = q1; psq [o + 2] = q2; psq [o + 3] = q3;
}

__global__ void bn_finalize(const double* __restrict__ psum, const double* __restrict__ psq,
                            const float* __restrict__ g0, const float* __restrict__ g1,
                            const float* __restrict__ g2,
                            float* __restrict__ meanv, float* __restrict__ Av,
                            int N, int RB, double invM)
{
  int z = blockIdx.y;
  const float* g = (z == 0) ? g0 : ((z == 1) ? g1 : g2);
  int c = blockIdx.x * blockDim.x + threadIdx.x;
  double s = 0.0, q = 0.0;
  for (int rb = 0; rb < RB; ++rb) {
    s += psum[((size_t)z * RB + rb) * N + c];
    q += psq [((size_t)z * RB + rb) * N + c];
  }
  double m = s * invM;
  double var = q * invM - m * m;
  if (var < 0.0) var = 0.0;
  meanv[(size_t)z * N + c] = (float)m;
  Av[(size_t)z * N + c] = g[(size_t)c] * rsqrtf((float)var + EPS);
}

// spike(bn(Y)) -> bf16 0/1, z-batched (q/k/v)
__global__ void bn_spike3_bf16(const float* __restrict__ Y, const float* __restrict__ meanv,
                               const float* __restrict__ Av,
                               const float* __restrict__ be0, const float* __restrict__ be1,
                               const float* __restrict__ be2,
                               unsigned short* __restrict__ S0, unsigned short* __restrict__ S1,
                               unsigned short* __restrict__ S2, int MN, int N)
{
  int z = blockIdx.y;
  const float* Yz = Y + (size_t)z * MN;
  const float* beta = (z == 0) ? be0 : ((z == 1) ? be1 : be2);
  unsigned short* S = (z == 0) ? S0 : ((z == 1) ? S1 : S2);
  const float* mz = meanv + (size_t)z * N;
  const float* az = Av + (size_t)z * N;
  size_t base = ((size_t)blockIdx.x * 256 + threadIdx.x) * 4;
  int c0 = (int)(base & (size_t)(N - 1));
  float4 y = *reinterpret_cast<const float4*>(&Yz[base]);
  ushort4 o;
  o.x = ((y.x - mz[c0 + 0]) * az[c0 + 0] + beta[c0 + 0] >= 2.0f) ? 0x3F80 : 0;
  o.y = ((y.y - mz[c0 + 1]) * az[c0 + 1] + beta[c0 + 1] >= 2.0f) ? 0x3F80 : 0;
  o.z = ((y.z - mz[c0 + 2]) * az[c0 + 2] + beta[c0 + 2] >= 2.0f) ? 0x3F80 : 0;
  o.w = ((y.w - mz[c0 + 3]) * az[c0 + 3] + beta[c0 + 3] >= 2.0f) ? 0x3F80 : 0;
  *reinterpret_cast<ushort4*>(&S[base]) = o;
}

// spike(bn(Y)) -> fp32 0/1 (final output)
__global__ void bn_spike_f32(const float* __restrict__ Y, const float* __restrict__ meanv,
                             const float* __restrict__ Av, const float* __restrict__ beta,
                             float* __restrict__ S, int N)
{
  size_t base = ((size_t)blockIdx.x * 256 + threadIdx.x) * 4;
  int c0 = (int)(base & (size_t)(N - 1));
  float4 y = *reinterpret_cast<const float4*>(&Y[base]);
  float4 o;
  o.x = ((y.x - meanv[c0 + 0]) * Av[c0 + 0] + beta[c0 + 0] >= 2.0f) ? 1.f : 0.f;
  o.y = ((y.y - meanv[c0 + 1]) * Av[c0 + 1] + beta[c0 + 1] >= 2.0f) ? 1.f : 0.f;
  o.z = ((y.z - meanv[c0 + 2]) * Av[c0 + 2] + beta[c0 + 2] >= 2.0f) ? 1.f : 0.f;
  o.w = ((y.w - meanv[c0 + 3]) * Av[c0 + 3] + beta[c0 + 3] >= 2.0f) ? 1.f : 0.f;
  *reinterpret_cast<float4*>(&S[base]) = o;
}

// =============== energy ===============
__global__ void energy_kernel(const unsigned short* __restrict__ qb,
                              const unsigned short* __restrict__ kb,
                              float* __restrict__ energy, int Ntok, int D)
{
  int bh = blockIdx.x;
  int b = bh >> 4, h = bh & 15;
  const unsigned short* qp = qb + (size_t)b * Ntok * D + h * 64;
  const unsigned short* kp = kb + (size_t)b * Ntok * D + h * 64;
  int tid = threadIdx.x;
  int cnt = 0;
  int tot = Ntok * 8;
  for (int idx = tid; idx < tot; idx += 256) {
    int n = idx >> 3, c8 = (idx & 7) * 8;
    u16x8 q = *reinterpret_cast<const u16x8*>(&qp[(size_t)n * D + c8]);
    u16x8 k = *reinterpret_cast<const u16x8*>(&kp[(size_t)n * D + c8]);
#pragma unroll
    for (int e = 0; e < 8; ++e) cnt += (int)((q[e] & k[e]) >> 7) & 1;
  }
  __shared__ int red[256];
  red[tid] = cnt;
  __syncthreads();
  for (int off = 128; off; off >>= 1) {
    if (tid < off) red[tid] += red[tid + off];
    __syncthreads();
  }
  if (tid == 0) energy[bh] = (float)red[0] / (float)Ntok;
}

// =============== gate ===============
__global__ void gate_kernel(const float* __restrict__ energy, const float* __restrict__ Wg,
                            const float* __restrict__ bg, float* __restrict__ gate, int D)
{
  int b = blockIdx.x >> 4, hp = blockIdx.x & 15;
  int tid = threadIdx.x;
  float e[16];
#pragma unroll
  for (int h = 0; h < 16; ++h) e[h] = energy[b * 16 + h];
  float s = 0.f;
  for (int j = tid; j < D; j += 256) s = fmaf(e[j & 15], Wg[(size_t)hp * D + j], s);
  __shared__ float red[256];
  red[tid] = s;
  __syncthreads();
  for (int off = 128; off; off >>= 1) {
    if (tid < off) red[tid] += red[tid + off];
    __syncthreads();
  }
  if (tid == 0) gate[blockIdx.x] = (red[0] + bg[hp] >= 0.5f) ? 1.f : 0.f;
}

// =============== gated attention + spike -> xat2 bf16 [4096][2048] = [s|s] ===============
__global__ __launch_bounds__(256) void attn_kernel(
    const unsigned short* __restrict__ qb, const unsigned short* __restrict__ kb,
    const unsigned short* __restrict__ vb, const float* __restrict__ gate,
    unsigned short* __restrict__ xs, int Ntok, int D, float scale)
{
  int bh = blockIdx.x;
  int b = bh >> 4, h = bh & 15;
  int n0 = blockIdx.y * 32;
  int tid = threadIdx.x;
  unsigned short* outbase = xs + (size_t)(b * Ntok + n0) * 2048 + h * 64;

  if (gate[bh] == 0.f) {
    ushort4 zv = {0, 0, 0, 0};
    for (int i = tid; i < 32 * 16; i += 256) {
      int r = i >> 4, c4 = (i & 15) << 2;
      *reinterpret_cast<ushort4*>(&outbase[(size_t)r * 2048 + c4]) = zv;
      *reinterpret_cast<ushort4*>(&outbase[(size_t)r * 2048 + 1024 + c4]) = zv;
    }
    return;
  }

  __shared__ float qs[32][68], ks[32][68], vs[32][68], Ss[32][36];
  const unsigned short* qg = qb + (size_t)b * Ntok * D + h * 64;
  const unsigned short* kg = kb + (size_t)b * Ntok * D + h * 64;
  const unsigned short* vg = vb + (size_t)b * Ntok * D + h * 64;

  {
    int r = tid >> 3, c8 = (tid & 7) * 8;
    u16x8 t = *reinterpret_cast<const u16x8*>(&qg[(size_t)(n0 + r) * D + c8]);
#pragma unroll
    for (int e = 0; e < 8; ++e) qs[r][c8 + e] = bf2f(t[e]);
  }

  float acc[8];
#pragma unroll
  for (int j = 0; j < 8; ++j) acc[j] = 0.f;
  const int nloc = tid >> 3;
  const int dd0 = (tid & 7) * 8;

  for (int mt = 0; mt < Ntok / 32; ++mt) {
    int m0 = mt * 32;
    __syncthreads();
    {
      int r = tid >> 3, c8 = (tid & 7) * 8;
      u16x8 tk = *reinterpret_cast<const u16x8*>(&kg[(size_t)(m0 + r) * D + c8]);
      u16x8 tv = *reinterpret_cast<const u16x8*>(&vg[(size_t)(m0 + r) * D + c8]);
#pragma unroll
      for (int e = 0; e < 8; ++e) { ks[r][c8 + e] = bf2f(tk[e]); vs[r][c8 + e] = bf2f(tv[e]); }
    }
    __syncthreads();
    {
      int np = tid >> 3;
      int mp0 = (tid & 7) * 4;
      float s0 = 0.f, s1 = 0.f, s2 = 0.f, s3 = 0.f;
#pragma unroll 8
      for (int d = 0; d < 64; ++d) {
        float qv = qs[np][d];
        s0 = fmaf(qv, ks[mp0 + 0][d], s0);
        s1 = fmaf(qv, ks[mp0 + 1][d], s1);
        s2 = fmaf(qv, ks[mp0 + 2][d], s2);
        s3 = fmaf(qv, ks[mp0 + 3][d], s3);
      }
      Ss[np][mp0 + 0] = s0; Ss[np][mp0 + 1] = s1;
      Ss[np][mp0 + 2] = s2; Ss[np][mp0 + 3] = s3;
    }
    __syncthreads();
#pragma unroll 8
    for (int mp = 0; mp < 32; ++mp) {
      float sv = Ss[nloc][mp];
#pragma unroll
      for (int j = 0; j < 8; ++j) acc[j] = fmaf(sv, vs[mp][dd0 + j], acc[j]);
    }
  }

#pragma unroll
  for (int j = 0; j < 8; ++j) {
    float x = scale * acc[j];
    unsigned short sp = (x >= 1.0f) ? 0x3F80 : 0;
    outbase[(size_t)nloc * 2048 + dd0 + j] = sp;
    outbase[(size_t)nloc * 2048 + 1024 + dd0 + j] = sp;
  }
}

// ======================================================================
extern "C" void kernel_launch(void* const* d_in, const int* in_sizes, int n_in,
                              void* d_out, int out_size, void* d_ws, size_t ws_size,
                              hipStream_t stream)
{
  (void)in_sizes; (void)n_in; (void)out_size; (void)ws_size;
  const int B = 4, Ntok = 1024, D = 1024;
  const int M = B * Ntok;                       // 4096
  const float scale = 0.5946035575013605f;      // 64^(-1/8)

  const float* x     = (const float*)d_in[0];
  const float* Wq    = (const float*)d_in[1];
  const float* bq    = (const float*)d_in[2];
  const float* gq    = (const float*)d_in[3];
  const float* betaq = (const float*)d_in[4];
  const float* Wk    = (const float*)d_in[5];
  const float* bk    = (const float*)d_in[6];
  const float* gk    = (const float*)d_in[7];
  const float* betak = (const float*)d_in[8];
  const float* Wv    = (const float*)d_in[9];
  const float* bv    = (const float*)d_in[10];
  const float* gv    = (const float*)d_in[11];
  const float* betav = (const float*)d_in[12];
  const float* Wp    = (const float*)d_in[13];
  const float* bp    = (const float*)d_in[14];
  const float* gp    = (const float*)d_in[15];
  const float* betap = (const float*)d_in[16];
  const float* Wg    = (const float*)d_in[17];
  const float* bg    = (const float*)d_in[18];

  char* w = (char*)d_ws;
  const size_t MB = 1024 * 1024;
  float*          Y3    = (float*)(w + 0 * MB);             // 48 MB [3][4096][1024]
  unsigned short* xat2  = (unsigned short*)(w + 0 * MB);    // alias, 16 MB [4096][2048]
  float*          Yp    = (float*)(w + 16 * MB);            // 16 MB
  unsigned short* Wpcat = (unsigned short*)(w + 32 * MB);   // 4 MB [1024][2048]
  unsigned short* Xh    = (unsigned short*)(w + 48 * MB);   // 8 MB
  unsigned short* Wh3   = (unsigned short*)(w + 56 * MB);   // 6 MB
  unsigned short* qb2   = (unsigned short*)(w + 62 * MB);   // 8 MB
  unsigned short* kb2   = (unsigned short*)(w + 70 * MB);   // 8 MB
  unsigned short* vb2   = (unsigned short*)(w + 78 * MB);   // 8 MB
  double* psum   = (double*)(w + 86 * MB);                  // 3*64*1024*8 = 1.5 MB
  double* psq    = (double*)(w + 88 * MB);                  // 1.5 MB
  float*  meanv  = (float*)(w + 90 * MB);                   // 12 KB
  float*  Av     = (float*)(w + 90 * MB + 16384);           // 12 KB
  float*  energy = (float*)(w + 90 * MB + 32768);
  float*  gate   = (float*)(w + 90 * MB + 32768 + 256);

  const int RB = 64;                   // row-blocks per z
  const int rowsPerBlk = M / RB;       // 64
  float* out = (float*)d_out;

  // ---- converts ----
  conv_x_kernel<<<dim3((M * D) / 1024), 256, 0, stream>>>(x, Xh);
  conv_w3_kernel<<<dim3((D * D) / 1024, 3), 256, 0, stream>>>(Wq, Wk, Wv, Wh3);

  // ---- q/k/v batched: GEMM + BN + spike ----
  gemm3_bf16_bt<<<dim3(D / 128, M / 128, 3), 256, 0, stream>>>(
      Xh, Wh3, Wh3 + (size_t)D * D, Wh3 + 2 * (size_t)D * D, bq, bk, bv, Y3, M, D, 1024);
  bn_stats<<<dim3(RB, 3), 256, 0, stream>>>(Y3, psum, psq, M, D, rowsPerBlk);
  bn_finalize<<<dim3(D / 256, 3), 256, 0, stream>>>(psum, psq, gq, gk, gv, meanv, Av, D, RB, 1.0 / M);
  bn_spike3_bf16<<<dim3((M * D) / 1024, 3), 256, 0, stream>>>(
      Y3, meanv, Av, betaq, betak, betav, qb2, kb2, vb2, M * D, D);

  // ---- energy + gate ----
  energy_kernel<<<dim3(64), 256, 0, stream>>>(qb2, kb2, energy, Ntok, D);
  gate_kernel<<<dim3(64), 256, 0, stream>>>(energy, Wg, bg, gate, D);

  // ---- gated attention + spike -> xat2 ([s|s] bf16) ----
  attn_kernel<<<dim3(64, Ntok / 32), 256, 0, stream>>>(qb2, kb2, vb2, gate, xat2, Ntok, D, scale);

  // ---- p branch: A=[s|s] (exact), B=[Wp_hi|Wp_lo], K=2048 ----
  split_wp_kernel<<<dim3((D * D) / 1024), 256, 0, stream>>>(Wp, Wpcat);
  gemm3_bf16_bt<<<dim3(D / 128, M / 128, 1), 256, 0, stream>>>(
      xat2, Wpcat, Wpcat, Wpcat, bp, bp, bp, Yp, M, D, 2048);
  bn_stats<<<dim3(RB, 1), 256, 0, stream>>>(Yp, psum, psq, M, D, rowsPerBlk);
  bn_finalize<<<dim3(D / 256, 1), 256, 0, stream>>>(psum, psq, gp, gp, gp, meanv, Av, D, RB, 1.0 / M);
  bn_spike_f32<<<dim3((M * D) / 1024), 256, 0, stream>>>(Yp, meanv, Av, betap, out, D);
}

// Round 5
// 112.668 us; speedup vs baseline: 9.5559x; 1.8939x over previous
//
#include <hip/hip_runtime.h>
#include <cstddef>
#include <cstdint>

#define EPS 1e-5f

typedef __bf16 bf16x8 __attribute__((ext_vector_type(8)));
typedef float f32x4 __attribute__((ext_vector_type(4)));
typedef unsigned short u16x8 __attribute__((ext_vector_type(8)));

__device__ __forceinline__ unsigned short f2bf(float f) {
  unsigned u = __builtin_bit_cast(unsigned, f);
  unsigned r = u + 0x7FFFu + ((u >> 16) & 1u);
  return (unsigned short)(r >> 16);
}
__device__ __forceinline__ float bf2f(unsigned short h) {
  unsigned u = (unsigned)h << 16;
  return __builtin_bit_cast(float, u);
}

__device__ __forceinline__ void gl_lds16(const void* g, void* l) {
  __builtin_amdgcn_global_load_lds(
      (const __attribute__((address_space(1))) unsigned int*)g,
      (__attribute__((address_space(3))) unsigned int*)l, 16, 0, 0);
}

// =============== bf16 MFMA GEMM + fused BN partial stats ===============
// Y[z][M][N] (bf16) = A[M][Kc] @ Wz[N][Kc]^T + bias_z ; psum/psq[z][32][N] fp64.
// 128x128 tile, BK=64, 4 waves; XOR-swizzled LDS; XCD-chunked block swizzle.
// SKIP: per-batch early-out when gate[b,:] all zero (A rows algebraically 0).
template <bool SKIP>
__global__ __launch_bounds__(256) void gemm3s_bf16_bt(
    const unsigned short* __restrict__ A,
    const unsigned short* __restrict__ W0, const unsigned short* __restrict__ W1,
    const unsigned short* __restrict__ W2,
    const float* __restrict__ b0, const float* __restrict__ b1, const float* __restrict__ b2,
    unsigned short* __restrict__ Y, double* __restrict__ psum, double* __restrict__ psq,
    const float* __restrict__ gate, int M, int N, int Kc)
{
  __shared__ unsigned short As[128 * 64];   // 16 KB (reused as f32 reduce buffer)
  __shared__ unsigned short Bs[128 * 64];   // 16 KB
  const int tid = threadIdx.x;

  // XCD-chunked swizzle: consecutive work ids (x fastest) land on one XCD.
  const int bid = blockIdx.x + (blockIdx.y << 3) + (blockIdx.z << 8);
  const int nwg = (int)gridDim.z << 8;           // 8*32 per z
  const int cpx = nwg >> 3;
  const int sw = (bid & 7) * cpx + (bid >> 3);
  const int bx = sw & 7, by = (sw >> 3) & 31, z = sw >> 8;

  const unsigned short* Bm = (z == 0) ? W0 : ((z == 1) ? W1 : W2);
  const float* bias = (z == 0) ? b0 : ((z == 1) ? b1 : b2);
  unsigned short* Yz = Y + (size_t)z * M * N;

  const int bm = by * 128;
  const int bn = bx * 128;

  const int lane = tid & 63;
  const int w = tid >> 6;
  const int wr = w >> 1, wc = w & 1;       // wave tile 64x64
  const int l15 = lane & 15, g = lane >> 4;

  f32x4 acc[4][4] = {};

  bool skip = false;
  if (SKIP) {
    float fnz = 0.f;
    int batch = by >> 3;
#pragma unroll
    for (int h = 0; h < 16; ++h) fnz += gate[batch * 16 + h];
    skip = (fnz == 0.f);
  }

  if (!skip) {
    const unsigned short* aSrc[4]; unsigned short* aDst[4];
    const unsigned short* bSrc[4]; unsigned short* bDst[4];
#pragma unroll
    for (int c = 0; c < 4; ++c) {
      int S = c * 256 + tid;
      int row = S >> 3, sp = S & 7;
      int sl = sp ^ (row & 7);
      aSrc[c] = A  + (size_t)(bm + row) * Kc + sl * 8;
      aDst[c] = &As[S * 8];
      bSrc[c] = Bm + (size_t)(bn + row) * Kc + sl * 8;
      bDst[c] = &Bs[S * 8];
    }

    int aOff[4][2], bOff[4][2];
#pragma unroll
    for (int i = 0; i < 4; ++i)
#pragma unroll
      for (int t = 0; t < 2; ++t) {
        int rowA = wr * 64 + i * 16 + l15;
        aOff[i][t] = rowA * 64 + ((t * 4 + g) ^ (rowA & 7)) * 8;
        int rowB = wc * 64 + i * 16 + l15;
        bOff[i][t] = rowB * 64 + ((t * 4 + g) ^ (rowB & 7)) * 8;
      }

    const int nk = Kc >> 6;
    for (int kt = 0; kt < nk; ++kt) {
      __syncthreads();
#pragma unroll
      for (int c = 0; c < 4; ++c) { gl_lds16(aSrc[c], aDst[c]); aSrc[c] += 64; }
#pragma unroll
      for (int c = 0; c < 4; ++c) { gl_lds16(bSrc[c], bDst[c]); bSrc[c] += 64; }
      __syncthreads();
#pragma unroll
      for (int t = 0; t < 2; ++t) {
        bf16x8 af[4], bfr[4];
#pragma unroll
        for (int i = 0; i < 4; ++i) af[i] = *(const bf16x8*)&As[aOff[i][t]];
#pragma unroll
        for (int j = 0; j < 4; ++j) bfr[j] = *(const bf16x8*)&Bs[bOff[j][t]];
#pragma unroll
        for (int i = 0; i < 4; ++i)
#pragma unroll
          for (int j = 0; j < 4; ++j)
            acc[i][j] = __builtin_amdgcn_mfma_f32_16x16x32_bf16(af[i], bfr[j], acc[i][j], 0, 0, 0);
      }
    }
  }

  // ---- epilogue: bf16 store + per-column partial sums (of stored values) ----
  const int r0 = bm + wr * 64 + g * 4;
  float csum[4], csq[4];
#pragma unroll
  for (int j = 0; j < 4; ++j) { csum[j] = 0.f; csq[j] = 0.f; }
#pragma unroll
  for (int j = 0; j < 4; ++j) {
    int col = bn + wc * 64 + j * 16 + l15;
    float bv = bias[col];
#pragma unroll
    for (int i = 0; i < 4; ++i)
#pragma unroll
      for (int r = 0; r < 4; ++r) {
        float yv = acc[i][j][r] + bv;
        unsigned short h = f2bf(yv);
        float yb = bf2f(h);
        Yz[(size_t)(r0 + i * 16 + r) * N + col] = h;
        csum[j] += yb;
        csq[j] += yb * yb;
      }
  }
  __syncthreads();
  float* Ls = (float*)As;                       // 8 slots x 128 cols, sums then sqs
  const int slot = wr * 4 + g;
#pragma unroll
  for (int j = 0; j < 4; ++j) {
    int ci = wc * 64 + j * 16 + l15;
    Ls[slot * 128 + ci] = csum[j];
    Ls[1024 + slot * 128 + ci] = csq[j];
  }
  __syncthreads();
  if (tid < 128) {
    double s = 0.0, q = 0.0;
#pragma unroll
    for (int sl = 0; sl < 8; ++sl) {
      s += (double)Ls[sl * 128 + tid];
      q += (double)Ls[1024 + sl * 128 + tid];
    }
    size_t o = ((size_t)z * 32 + by) * N + bn + tid;
    psum[o] = s;
    psq[o] = q;
  }
}

// =============== converts ===============
__global__ void conv_x_kernel(const float* __restrict__ X, unsigned short* __restrict__ O)
{
  size_t base = ((size_t)blockIdx.x * 256 + threadIdx.x) * 4;
  float4 xv = *reinterpret_cast<const float4*>(&X[base]);
  ushort4 o;
  o.x = f2bf(xv.x); o.y = f2bf(xv.y); o.z = f2bf(xv.z); o.w = f2bf(xv.w);
  *reinterpret_cast<ushort4*>(&O[base]) = o;
}

__global__ void conv_w3_kernel(const float* __restrict__ W0, const float* __restrict__ W1,
                               const float* __restrict__ W2, unsigned short* __restrict__ O)
{
  int z = blockIdx.y;
  const float* W = (z == 0) ? W0 : ((z == 1) ? W1 : W2);
  size_t base = ((size_t)blockIdx.x * 256 + threadIdx.x) * 4;
  float4 xv = *reinterpret_cast<const float4*>(&W[base]);
  ushort4 o;
  o.x = f2bf(xv.x); o.y = f2bf(xv.y); o.z = f2bf(xv.z); o.w = f2bf(xv.w);
  *reinterpret_cast<ushort4*>(&O[(size_t)z * 1024 * 1024 + base]) = o;
}

// Wp [1024][1024] -> O [1024][2048] = [hi | lo]
__global__ void split_wp_kernel(const float* __restrict__ X, unsigned short* __restrict__ O)
{
  size_t base = ((size_t)blockIdx.x * 256 + threadIdx.x) * 4;
  int r = (int)(base >> 10), c = (int)(base & 1023);
  float4 xv = *reinterpret_cast<const float4*>(&X[base]);
  ushort4 hi, lo;
  hi.x = f2bf(xv.x); lo.x = f2bf(xv.x - bf2f(hi.x));
  hi.y = f2bf(xv.y); lo.y = f2bf(xv.y - bf2f(hi.y));
  hi.z = f2bf(xv.z); lo.z = f2bf(xv.z - bf2f(hi.z));
  hi.w = f2bf(xv.w); lo.w = f2bf(xv.w - bf2f(hi.w));
  unsigned short* Or = O + (size_t)r * 2048;
  *reinterpret_cast<ushort4*>(&Or[c]) = hi;
  *reinterpret_cast<ushort4*>(&Or[1024 + c]) = lo;
}

// =============== BN finalize (RB=32 partial blocks) ===============
__global__ void bn_finalize(const double* __restrict__ psum, const double* __restrict__ psq,
                            const float* __restrict__ g0, const float* __restrict__ g1,
                            const float* __restrict__ g2,
                            float* __restrict__ meanv, float* __restrict__ Av,
                            int N, double invM)
{
  int z = blockIdx.y;
  const float* g = (z == 0) ? g0 : ((z == 1) ? g1 : g2);
  int c = blockIdx.x * blockDim.x + threadIdx.x;
  double s = 0.0, q = 0.0;
  for (int rb = 0; rb < 32; ++rb) {
    s += psum[((size_t)z * 32 + rb) * N + c];
    q += psq [((size_t)z * 32 + rb) * N + c];
  }
  double m = s * invM;
  double var = q * invM - m * m;
  if (var < 0.0) var = 0.0;
  meanv[(size_t)z * N + c] = (float)m;
  Av[(size_t)z * N + c] = g[(size_t)c] * rsqrtf((float)var + EPS);
}

// spike(bn(Y)) from bf16 Y -> bf16 0/1, z-batched (q/k/v); 8 elems/thread
__global__ void bn_spike3_bf16(const unsigned short* __restrict__ Y,
                               const float* __restrict__ meanv, const float* __restrict__ Av,
                               const float* __restrict__ be0, const float* __restrict__ be1,
                               const float* __restrict__ be2,
                               unsigned short* __restrict__ S0, unsigned short* __restrict__ S1,
                               unsigned short* __restrict__ S2, int MN, int N)
{
  int z = blockIdx.y;
  const unsigned short* Yz = Y + (size_t)z * MN;
  const float* beta = (z == 0) ? be0 : ((z == 1) ? be1 : be2);
  unsigned short* S = (z == 0) ? S0 : ((z == 1) ? S1 : S2);
  const float* mz = meanv + (size_t)z * N;
  const float* az = Av + (size_t)z * N;
  size_t base = ((size_t)blockIdx.x * 256 + threadIdx.x) * 8;
  int c0 = (int)(base & (size_t)(N - 1));
  u16x8 y8 = *reinterpret_cast<const u16x8*>(&Yz[base]);
  u16x8 o;
#pragma unroll
  for (int e = 0; e < 8; ++e) {
    float y = bf2f(y8[e]);
    o[e] = ((y - mz[c0 + e]) * az[c0 + e] + beta[c0 + e] >= 2.0f) ? 0x3F80 : 0;
  }
  *reinterpret_cast<u16x8*>(&S[base]) = o;
}

// spike(bn(Y)) from bf16 Y -> fp32 0/1 (final output); 8 elems/thread
__global__ void bn_spike_f32(const unsigned short* __restrict__ Y,
                             const float* __restrict__ meanv, const float* __restrict__ Av,
                             const float* __restrict__ beta, float* __restrict__ S, int N)
{
  size_t base = ((size_t)blockIdx.x * 256 + threadIdx.x) * 8;
  int c0 = (int)(base & (size_t)(N - 1));
  u16x8 y8 = *reinterpret_cast<const u16x8*>(&Y[base]);
  float4 o0, o1;
  o0.x = ((bf2f(y8[0]) - meanv[c0 + 0]) * Av[c0 + 0] + beta[c0 + 0] >= 2.0f) ? 1.f : 0.f;
  o0.y = ((bf2f(y8[1]) - meanv[c0 + 1]) * Av[c0 + 1] + beta[c0 + 1] >= 2.0f) ? 1.f : 0.f;
  o0.z = ((bf2f(y8[2]) - meanv[c0 + 2]) * Av[c0 + 2] + beta[c0 + 2] >= 2.0f) ? 1.f : 0.f;
  o0.w = ((bf2f(y8[3]) - meanv[c0 + 3]) * Av[c0 + 3] + beta[c0 + 3] >= 2.0f) ? 1.f : 0.f;
  o1.x = ((bf2f(y8[4]) - meanv[c0 + 4]) * Av[c0 + 4] + beta[c0 + 4] >= 2.0f) ? 1.f : 0.f;
  o1.y = ((bf2f(y8[5]) - meanv[c0 + 5]) * Av[c0 + 5] + beta[c0 + 5] >= 2.0f) ? 1.f : 0.f;
  o1.z = ((bf2f(y8[6]) - meanv[c0 + 6]) * Av[c0 + 6] + beta[c0 + 6] >= 2.0f) ? 1.f : 0.f;
  o1.w = ((bf2f(y8[7]) - meanv[c0 + 7]) * Av[c0 + 7] + beta[c0 + 7] >= 2.0f) ? 1.f : 0.f;
  *reinterpret_cast<float4*>(&S[base]) = o0;
  *reinterpret_cast<float4*>(&S[base + 4]) = o1;
}

// =============== energy ===============
__global__ void energy_kernel(const unsigned short* __restrict__ qb,
                              const unsigned short* __restrict__ kb,
                              float* __restrict__ energy, int Ntok, int D)
{
  int bh = blockIdx.x;
  int b = bh >> 4, h = bh & 15;
  const unsigned short* qp = qb + (size_t)b * Ntok * D + h * 64;
  const unsigned short* kp = kb + (size_t)b * Ntok * D + h * 64;
  int tid = threadIdx.x;
  int cnt = 0;
  int tot = Ntok * 8;
  for (int idx = tid; idx < tot; idx += 256) {
    int n = idx >> 3, c8 = (idx & 7) * 8;
    u16x8 q = *reinterpret_cast<const u16x8*>(&qp[(size_t)n * D + c8]);
    u16x8 k = *reinterpret_cast<const u16x8*>(&kp[(size_t)n * D + c8]);
#pragma unroll
    for (int e = 0; e < 8; ++e) cnt += (int)((q[e] & k[e]) >> 7) & 1;
  }
  __shared__ int red[256];
  red[tid] = cnt;
  __syncthreads();
  for (int off = 128; off; off >>= 1) {
    if (tid < off) red[tid] += red[tid + off];
    __syncthreads();
  }
  if (tid == 0) energy[bh] = (float)red[0] / (float)Ntok;
}

// =============== gate ===============
__global__ void gate_kernel(const float* __restrict__ energy, const float* __restrict__ Wg,
                            const float* __restrict__ bg, float* __restrict__ gate, int D)
{
  int b = blockIdx.x >> 4, hp = blockIdx.x & 15;
  int tid = threadIdx.x;
  float e[16];
#pragma unroll
  for (int h = 0; h < 16; ++h) e[h] = energy[b * 16 + h];
  float s = 0.f;
  for (int j = tid; j < D; j += 256) s = fmaf(e[j & 15], Wg[(size_t)hp * D + j], s);
  __shared__ float red[256];
  red[tid] = s;
  __syncthreads();
  for (int off = 128; off; off >>= 1) {
    if (tid < off) red[tid] += red[tid + off];
    __syncthreads();
  }
  if (tid == 0) gate[blockIdx.x] = (red[0] + bg[hp] >= 0.5f) ? 1.f : 0.f;
}

// =============== gated attention + spike -> xat2 bf16 [4096][2048] = [s|s] ===============
__global__ __launch_bounds__(256) void attn_kernel(
    const unsigned short* __restrict__ qb, const unsigned short* __restrict__ kb,
    const unsigned short* __restrict__ vb, const float* __restrict__ gate,
    unsigned short* __restrict__ xs, int Ntok, int D, float scale)
{
  int bh = blockIdx.x;
  int b = bh >> 4, h = bh & 15;
  int n0 = blockIdx.y * 32;
  int tid = threadIdx.x;
  unsigned short* outbase = xs + (size_t)(b * Ntok + n0) * 2048 + h * 64;

  if (gate[bh] == 0.f) {
    ushort4 zv = {0, 0, 0, 0};
    for (int i = tid; i < 32 * 16; i += 256) {
      int r = i >> 4, c4 = (i & 15) << 2;
      *reinterpret_cast<ushort4*>(&outbase[(size_t)r * 2048 + c4]) = zv;
      *reinterpret_cast<ushort4*>(&outbase[(size_t)r * 2048 + 1024 + c4]) = zv;
    }
    return;
  }

  __shared__ float qs[32][68], ks[32][68], vs[32][68], Ss[32][36];
  const unsigned short* qg = qb + (size_t)b * Ntok * D + h * 64;
  const unsigned short* kg = kb + (size_t)b * Ntok * D + h * 64;
  const unsigned short* vg = vb + (size_t)b * Ntok * D + h * 64;

  {
    int r = tid >> 3, c8 = (tid & 7) * 8;
    u16x8 t = *reinterpret_cast<const u16x8*>(&qg[(size_t)(n0 + r) * D + c8]);
#pragma unroll
    for (int e = 0; e < 8; ++e) qs[r][c8 + e] = bf2f(t[e]);
  }

  float acc[8];
#pragma unroll
  for (int j = 0; j < 8; ++j) acc[j] = 0.f;
  const int nloc = tid >> 3;
  const int dd0 = (tid & 7) * 8;

  for (int mt = 0; mt < Ntok / 32; ++mt) {
    int m0 = mt * 32;
    __syncthreads();
    {
      int r = tid >> 3, c8 = (tid & 7) * 8;
      u16x8 tk = *reinterpret_cast<const u16x8*>(&kg[(size_t)(m0 + r) * D + c8]);
      u16x8 tv = *reinterpret_cast<const u16x8*>(&vg[(size_t)(m0 + r) * D + c8]);
#pragma unroll
      for (int e = 0; e < 8; ++e) { ks[r][c8 + e] = bf2f(tk[e]); vs[r][c8 + e] = bf2f(tv[e]); }
    }
    __syncthreads();
    {
      int np = tid >> 3;
      int mp0 = (tid & 7) * 4;
      float s0 = 0.f, s1 = 0.f, s2 = 0.f, s3 = 0.f;
#pragma unroll 8
      for (int d = 0; d < 64; ++d) {
        float qv = qs[np][d];
        s0 = fmaf(qv, ks[mp0 + 0][d], s0);
        s1 = fmaf(qv, ks[mp0 + 1][d], s1);
        s2 = fmaf(qv, ks[mp0 + 2][d], s2);
        s3 = fmaf(qv, ks[mp0 + 3][d], s3);
      }
      Ss[np][mp0 + 0] = s0; Ss[np][mp0 + 1] = s1;
      Ss[np][mp0 + 2] = s2; Ss[np][mp0 + 3] = s3;
    }
    __syncthreads();
#pragma unroll 8
    for (int mp = 0; mp < 32; ++mp) {
      float sv = Ss[nloc][mp];
#pragma unroll
      for (int j = 0; j < 8; ++j) acc[j] = fmaf(sv, vs[mp][dd0 + j], acc[j]);
    }
  }

#pragma unroll
  for (int j = 0; j < 8; ++j) {
    float x = scale * acc[j];
    unsigned short sp = (x >= 1.0f) ? 0x3F80 : 0;
    outbase[(size_t)nloc * 2048 + dd0 + j] = sp;
    outbase[(size_t)nloc * 2048 + 1024 + dd0 + j] = sp;
  }
}

// ======================================================================
extern "C" void kernel_launch(void* const* d_in, const int* in_sizes, int n_in,
                              void* d_out, int out_size, void* d_ws, size_t ws_size,
                              hipStream_t stream)
{
  (void)in_sizes; (void)n_in; (void)out_size; (void)ws_size;
  const int B = 4, Ntok = 1024, D = 1024;
  const int M = B * Ntok;                       // 4096
  const float scale = 0.5946035575013605f;      // 64^(-1/8)

  const float* x     = (const float*)d_in[0];
  const float* Wq    = (const float*)d_in[1];
  const float* bq    = (const float*)d_in[2];
  const float* gq    = (const float*)d_in[3];
  const float* betaq = (const float*)d_in[4];
  const float* Wk    = (const float*)d_in[5];
  const float* bk    = (const float*)d_in[6];
  const float* gk    = (const float*)d_in[7];
  const float* betak = (const float*)d_in[8];
  const float* Wv    = (const float*)d_in[9];
  const float* bv    = (const float*)d_in[10];
  const float* gv    = (const float*)d_in[11];
  const float* betav = (const float*)d_in[12];
  const float* Wp    = (const float*)d_in[13];
  const float* bp    = (const float*)d_in[14];
  const float* gp    = (const float*)d_in[15];
  const float* betap = (const float*)d_in[16];
  const float* Wg    = (const float*)d_in[17];
  const float* bg    = (const float*)d_in[18];

  char* w = (char*)d_ws;
  const size_t MB = 1024 * 1024;
  unsigned short* Y3bf  = (unsigned short*)(w + 0 * MB);    // 24 MB [3][4096][1024]
  unsigned short* xat2  = (unsigned short*)(w + 0 * MB);    // alias, 16 MB [4096][2048] (Y3 dead)
  unsigned short* Yp    = (unsigned short*)(w + 24 * MB);   // 8 MB [4096][1024]
  unsigned short* Wpcat = (unsigned short*)(w + 32 * MB);   // 4 MB [1024][2048]
  unsigned short* Xh    = (unsigned short*)(w + 48 * MB);   // 8 MB
  unsigned short* Wh3   = (unsigned short*)(w + 56 * MB);   // 6 MB
  unsigned short* qb2   = (unsigned short*)(w + 62 * MB);   // 8 MB
  unsigned short* kb2   = (unsigned short*)(w + 70 * MB);   // 8 MB
  unsigned short* vb2   = (unsigned short*)(w + 78 * MB);   // 8 MB
  double* psum   = (double*)(w + 86 * MB);                  // 3*32*1024*8 = 768 KB
  double* psq    = (double*)(w + 87 * MB);                  // 768 KB
  float*  meanv  = (float*)(w + 88 * MB);                   // 12 KB
  float*  Av     = (float*)(w + 88 * MB + 16384);           // 12 KB
  float*  energy = (float*)(w + 88 * MB + 32768);
  float*  gate   = (float*)(w + 88 * MB + 32768 + 256);

  float* out = (float*)d_out;

  // ---- converts ----
  conv_x_kernel<<<dim3((M * D) / 1024), 256, 0, stream>>>(x, Xh);
  conv_w3_kernel<<<dim3((D * D) / 1024, 3), 256, 0, stream>>>(Wq, Wk, Wv, Wh3);
  split_wp_kernel<<<dim3((D * D) / 1024), 256, 0, stream>>>(Wp, Wpcat);

  // ---- q/k/v batched: GEMM(+stats) + finalize + spike ----
  gemm3s_bf16_bt<false><<<dim3(8, 32, 3), 256, 0, stream>>>(
      Xh, Wh3, Wh3 + (size_t)D * D, Wh3 + 2 * (size_t)D * D, bq, bk, bv,
      Y3bf, psum, psq, nullptr, M, D, 1024);
  bn_finalize<<<dim3(D / 256, 3), 256, 0, stream>>>(psum, psq, gq, gk, gv, meanv, Av, D, 1.0 / M);
  bn_spike3_bf16<<<dim3((M * D) / 2048, 3), 256, 0, stream>>>(
      Y3bf, meanv, Av, betaq, betak, betav, qb2, kb2, vb2, M * D, D);

  // ---- energy + gate ----
  energy_kernel<<<dim3(64), 256, 0, stream>>>(qb2, kb2, energy, Ntok, D);
  gate_kernel<<<dim3(64), 256, 0, stream>>>(energy, Wg, bg, gate, D);

  // ---- gated attention + spike -> xat2 ([s|s] bf16) ----
  attn_kernel<<<dim3(64, Ntok / 32), 256, 0, stream>>>(qb2, kb2, vb2, gate, xat2, Ntok, D, scale);

  // ---- p branch: A=[s|s], B=[Wp_hi|Wp_lo], K=2048; per-batch gate skip ----
  gemm3s_bf16_bt<true><<<dim3(8, 32, 1), 256, 0, stream>>>(
      xat2, Wpcat, Wpcat, Wpcat, bp, bp, bp, Yp, psum, psq, gate, M, D, 2048);
  bn_finalize<<<dim3(D / 256, 1), 256, 0, stream>>>(psum, psq, gp, gp, gp, meanv, Av, D, 1.0 / M);
  bn_spike_f32<<<dim3((M * D) / 2048), 256, 0, stream>>>(Yp, meanv, Av, betap, out, D);
}

// Round 6
// 78.994 us; speedup vs baseline: 13.6293x; 1.4263x over previous
//
#include <hip/hip_runtime.h>
#include <cstddef>
#include <cstdint>

#define EPS 1e-5f

typedef __bf16 bf16x8 __attribute__((ext_vector_type(8)));
typedef float f32x4 __attribute__((ext_vector_type(4)));
typedef unsigned short u16x8 __attribute__((ext_vector_type(8)));

__device__ __forceinline__ unsigned short f2bf(float f) {
  unsigned u = __builtin_bit_cast(unsigned, f);
  unsigned r = u + 0x7FFFu + ((u >> 16) & 1u);
  return (unsigned short)(r >> 16);
}
__device__ __forceinline__ float bf2f(unsigned short h) {
  unsigned u = (unsigned)h << 16;
  return __builtin_bit_cast(float, u);
}

__device__ __forceinline__ void gl_lds16(const void* g, void* l) {
  __builtin_amdgcn_global_load_lds(
      (const __attribute__((address_space(1))) unsigned int*)g,
      (__attribute__((address_space(3))) unsigned int*)l, 16, 0, 0);
}

// =============== bf16 MFMA GEMM, 2-phase prefetch dbuf + fused BN stats ===============
// MODE 0: plain (z selects W0/W1 via grid.z)
// MODE 1: per-batch skip of K-loop (p-branch; epilogue still writes bias + stats)
// MODE 2: full kernel skip when flags[0]==0 (v-branch; outputs unread in that case)
template <int MODE>
__global__ __launch_bounds__(256) void gemm_bf16_bt(
    const unsigned short* __restrict__ A,
    const unsigned short* __restrict__ W0, const unsigned short* __restrict__ W1,
    const float* __restrict__ b0, const float* __restrict__ b1,
    unsigned short* __restrict__ Y, double* __restrict__ psum, double* __restrict__ psq,
    const int* __restrict__ flags, int N, int Kc)
{
  if (MODE == 2) { if (flags[0] == 0) return; }

  __shared__ unsigned short As[2][8192];   // 2 x 16 KB
  __shared__ unsigned short Bs[2][8192];   // 2 x 16 KB
  const int tid = threadIdx.x;

  // XCD-chunked swizzle
  const int bid = blockIdx.x + (blockIdx.y << 3) + (blockIdx.z << 8);
  const int nwg = (int)gridDim.z << 8;
  const int cpx = nwg >> 3;
  const int sw = (bid & 7) * cpx + (bid >> 3);
  const int bx = sw & 7, by = (sw >> 3) & 31, z = sw >> 8;

  const unsigned short* Bm = z ? W1 : W0;
  const float* bias = z ? b1 : b0;
  unsigned short* Yz = Y + (size_t)z * 4096 * N;

  const int bm = by * 128, bn = bx * 128;
  const int lane = tid & 63, w = tid >> 6;
  const int wr = w >> 1, wc = w & 1;            // wave tile 64x64
  const int l15 = lane & 15, g = lane >> 4;

  f32x4 acc[4][4] = {};

  bool skip = false;
  if (MODE == 1) skip = (flags[1 + (by >> 3)] == 0);

  if (!skip) {
    const unsigned short* aSrc[4]; const unsigned short* bSrc[4]; int dOff[4];
#pragma unroll
    for (int c = 0; c < 4; ++c) {
      int S = c * 256 + tid;
      int row = S >> 3, sp = S & 7;
      int sl = sp ^ (row & 7);
      aSrc[c] = A  + (size_t)(bm + row) * Kc + sl * 8;
      bSrc[c] = Bm + (size_t)(bn + row) * Kc + sl * 8;
      dOff[c] = S * 8;
    }
    int aOff[4][2], bOff[4][2];
#pragma unroll
    for (int i = 0; i < 4; ++i)
#pragma unroll
      for (int t = 0; t < 2; ++t) {
        int rowA = wr * 64 + i * 16 + l15;
        aOff[i][t] = rowA * 64 + ((t * 4 + g) ^ (rowA & 7)) * 8;
        int rowB = wc * 64 + i * 16 + l15;
        bOff[i][t] = rowB * 64 + ((t * 4 + g) ^ (rowB & 7)) * 8;
      }

    const int nk = Kc >> 6;
    // prologue: stage tile 0 into buf 0
#pragma unroll
    for (int c = 0; c < 4; ++c) { gl_lds16(aSrc[c], &As[0][dOff[c]]); aSrc[c] += 64; }
#pragma unroll
    for (int c = 0; c < 4; ++c) { gl_lds16(bSrc[c], &Bs[0][dOff[c]]); bSrc[c] += 64; }
    __syncthreads();

    int cur = 0;
    for (int kt = 0; kt < nk; ++kt) {
      if (kt + 1 < nk) {      // issue next-tile stage BEFORE compute (overlap)
#pragma unroll
        for (int c = 0; c < 4; ++c) { gl_lds16(aSrc[c], &As[cur ^ 1][dOff[c]]); aSrc[c] += 64; }
#pragma unroll
        for (int c = 0; c < 4; ++c) { gl_lds16(bSrc[c], &Bs[cur ^ 1][dOff[c]]); bSrc[c] += 64; }
      }
#pragma unroll
      for (int t = 0; t < 2; ++t) {
        bf16x8 af[4], bfr[4];
#pragma unroll
        for (int i = 0; i < 4; ++i) af[i] = *(const bf16x8*)&As[cur][aOff[i][t]];
#pragma unroll
        for (int j = 0; j < 4; ++j) bfr[j] = *(const bf16x8*)&Bs[cur][bOff[j][t]];
#pragma unroll
        for (int i = 0; i < 4; ++i)
#pragma unroll
          for (int j = 0; j < 4; ++j)
            acc[i][j] = __builtin_amdgcn_mfma_f32_16x16x32_bf16(af[i], bfr[j], acc[i][j], 0, 0, 0);
      }
      __syncthreads();        // compiler emits vmcnt(0) lgkmcnt(0) drain here
      cur ^= 1;
    }
  }

  // ---- epilogue: bf16 store + per-column partials (of stored values) ----
  const int r0 = bm + wr * 64 + g * 4;
  float csum[4], csq[4];
#pragma unroll
  for (int j = 0; j < 4; ++j) { csum[j] = 0.f; csq[j] = 0.f; }
#pragma unroll
  for (int j = 0; j < 4; ++j) {
    int col = bn + wc * 64 + j * 16 + l15;
    float bv = bias[col];
#pragma unroll
    for (int i = 0; i < 4; ++i)
#pragma unroll
      for (int r = 0; r < 4; ++r) {
        float yv = acc[i][j][r] + bv;
        unsigned short h = f2bf(yv);
        float yb = bf2f(h);
        Yz[(size_t)(r0 + i * 16 + r) * N + col] = h;
        csum[j] += yb;
        csq[j] += yb * yb;
      }
  }
  __syncthreads();
  float* Ls = (float*)&As[0][0];                 // 8 slots x 128 cols, sums then sqs
  const int slot = wr * 4 + g;
#pragma unroll
  for (int j = 0; j < 4; ++j) {
    int ci = wc * 64 + j * 16 + l15;
    Ls[slot * 128 + ci] = csum[j];
    Ls[1024 + slot * 128 + ci] = csq[j];
  }
  __syncthreads();
  if (tid < 128) {
    double s = 0.0, q = 0.0;
#pragma unroll
    for (int sl = 0; sl < 8; ++sl) {
      s += (double)Ls[sl * 128 + tid];
      q += (double)Ls[1024 + sl * 128 + tid];
    }
    size_t o = ((size_t)z * 32 + by) * N + bn + tid;
    psum[o] = s;
    psq[o] = q;
  }
}

// =============== prep: all fp32->bf16 converts in one kernel ===============
// blocks 0..2047: x -> Xh ; 2048..3583: Wq/Wk/Wv -> Wh3 ; 3584..4095: Wp -> [hi|lo]
__global__ void prep_kernel(const float* __restrict__ x,
                            const float* __restrict__ Wq, const float* __restrict__ Wk,
                            const float* __restrict__ Wv, const float* __restrict__ Wp,
                            unsigned short* __restrict__ Xh, unsigned short* __restrict__ Wh3,
                            unsigned short* __restrict__ Wpcat)
{
  int bid = blockIdx.x, tid = threadIdx.x;
  if (bid < 3584) {
    const float* src; unsigned short* dst; size_t base;
    if (bid < 2048) {
      src = x; dst = Xh; base = ((size_t)bid * 256 + tid) * 8;
    } else {
      int r = bid - 2048, z = r >> 9, blk = r & 511;
      src = (z == 0) ? Wq : ((z == 1) ? Wk : Wv);
      dst = Wh3 + (size_t)z * 1024 * 1024;
      base = ((size_t)blk * 256 + tid) * 8;
    }
    float4 a = *reinterpret_cast<const float4*>(&src[base]);
    float4 b = *reinterpret_cast<const float4*>(&src[base + 4]);
    u16x8 o;
    o[0] = f2bf(a.x); o[1] = f2bf(a.y); o[2] = f2bf(a.z); o[3] = f2bf(a.w);
    o[4] = f2bf(b.x); o[5] = f2bf(b.y); o[6] = f2bf(b.z); o[7] = f2bf(b.w);
    *reinterpret_cast<u16x8*>(&dst[base]) = o;
  } else {
    int blk = bid - 3584;
    size_t base = ((size_t)blk * 256 + tid) * 8;
    int r = (int)(base >> 10), c = (int)(base & 1023);
    float4 a = *reinterpret_cast<const float4*>(&Wp[base]);
    float4 b = *reinterpret_cast<const float4*>(&Wp[base + 4]);
    u16x8 hi, lo;
    hi[0] = f2bf(a.x); lo[0] = f2bf(a.x - bf2f(hi[0]));
    hi[1] = f2bf(a.y); lo[1] = f2bf(a.y - bf2f(hi[1]));
    hi[2] = f2bf(a.z); lo[2] = f2bf(a.z - bf2f(hi[2]));
    hi[3] = f2bf(a.w); lo[3] = f2bf(a.w - bf2f(hi[3]));
    hi[4] = f2bf(b.x); lo[4] = f2bf(b.x - bf2f(hi[4]));
    hi[5] = f2bf(b.y); lo[5] = f2bf(b.y - bf2f(hi[5]));
    hi[6] = f2bf(b.z); lo[6] = f2bf(b.z - bf2f(hi[6]));
    hi[7] = f2bf(b.w); lo[7] = f2bf(b.w - bf2f(hi[7]));
    unsigned short* Or = Wpcat + (size_t)r * 2048;
    *reinterpret_cast<u16x8*>(&Or[c]) = hi;
    *reinterpret_cast<u16x8*>(&Or[1024 + c]) = lo;
  }
}

// =============== BN finalize (32 partial blocks); optional flag-guard + zero duty ===============
__global__ void bn_finalize(const double* __restrict__ psum, const double* __restrict__ psq,
                            const float* __restrict__ g0, const float* __restrict__ g1,
                            float* __restrict__ meanv, float* __restrict__ Av,
                            const int* __restrict__ runflag,
                            int* __restrict__ zflags, int* __restrict__ zenergy,
                            int N, double invM)
{
  if (zflags && blockIdx.x == 0 && blockIdx.y == 0) {
    int t = threadIdx.x;
    if (t < 5) zflags[t] = 0;
    if (t >= 64 && t < 128) zenergy[t - 64] = 0;
  }
  if (runflag && runflag[0] == 0) return;
  int z = blockIdx.y;
  const float* g = z ? g1 : g0;
  int c = blockIdx.x * blockDim.x + threadIdx.x;
  double s = 0.0, q = 0.0;
  for (int rb = 0; rb < 32; ++rb) {
    s += psum[((size_t)z * 32 + rb) * N + c];
    q += psq [((size_t)z * 32 + rb) * N + c];
  }
  double m = s * invM;
  double var = q * invM - m * m;
  if (var < 0.0) var = 0.0;
  meanv[(size_t)z * N + c] = (float)m;
  Av[(size_t)z * N + c] = g[(size_t)c] * rsqrtf((float)var + EPS);
}

// =============== q/k spike + fused energy popcount (deterministic int atomics) ===============
// grid 512 blocks; each block: 8 rows (8192 elems per tensor), 4 iters x 8 elems/thread
__global__ void spike_qk_energy(const unsigned short* __restrict__ Yq,
                                const unsigned short* __restrict__ Yk,
                                const float* __restrict__ meanv, const float* __restrict__ Av,
                                const float* __restrict__ beq, const float* __restrict__ bek,
                                unsigned short* __restrict__ qb, unsigned short* __restrict__ kb,
                                int* __restrict__ energy_int, int N)
{
  const int tid = threadIdx.x;
  const int c0 = (tid * 8) & (N - 1);
  const int head = c0 >> 6;
  const int batch = blockIdx.x >> 7;
  const float* mq = meanv;            const float* aq = Av;
  const float* mk = meanv + N;        const float* ak = Av + N;
  __shared__ int bins[16];
  if (tid < 16) bins[tid] = 0;
  __syncthreads();
  int cnt = 0;
#pragma unroll
  for (int j = 0; j < 4; ++j) {
    size_t base = (size_t)blockIdx.x * 8192 + j * 2048 + tid * 8;
    u16x8 yq = *reinterpret_cast<const u16x8*>(&Yq[base]);
    u16x8 yk = *reinterpret_cast<const u16x8*>(&Yk[base]);
    u16x8 oq, ok;
#pragma unroll
    for (int e = 0; e < 8; ++e) {
      bool sq = (bf2f(yq[e]) - mq[c0 + e]) * aq[c0 + e] + beq[c0 + e] >= 2.0f;
      bool sk = (bf2f(yk[e]) - mk[c0 + e]) * ak[c0 + e] + bek[c0 + e] >= 2.0f;
      oq[e] = sq ? 0x3F80 : 0;
      ok[e] = sk ? 0x3F80 : 0;
      cnt += (sq && sk) ? 1 : 0;
    }
    *reinterpret_cast<u16x8*>(&qb[base]) = oq;
    *reinterpret_cast<u16x8*>(&kb[base]) = ok;
  }
  atomicAdd(&bins[head], cnt);
  __syncthreads();
  if (tid < 16) atomicAdd(&energy_int[batch * 16 + tid], bins[tid]);
}

// =============== v spike (flag-guarded) ===============
__global__ void spike_v(const unsigned short* __restrict__ Yv,
                        const float* __restrict__ meanv, const float* __restrict__ Av,
                        const float* __restrict__ beta, unsigned short* __restrict__ vb,
                        const int* __restrict__ flags, int N)
{
  if (flags[0] == 0) return;
  size_t base = ((size_t)blockIdx.x * 256 + threadIdx.x) * 8;
  int c0 = (int)(base & (size_t)(N - 1));
  u16x8 y8 = *reinterpret_cast<const u16x8*>(&Yv[base]);
  u16x8 o;
#pragma unroll
  for (int e = 0; e < 8; ++e)
    o[e] = ((bf2f(y8[e]) - meanv[c0 + e]) * Av[c0 + e] + beta[c0 + e] >= 2.0f) ? 0x3F80 : 0;
  *reinterpret_cast<u16x8*>(&vb[base]) = o;
}

// =============== final output spike ===============
__global__ void bn_spike_f32(const unsigned short* __restrict__ Y,
                             const float* __restrict__ meanv, const float* __restrict__ Av,
                             const float* __restrict__ beta, float* __restrict__ S, int N)
{
  size_t base = ((size_t)blockIdx.x * 256 + threadIdx.x) * 8;
  int c0 = (int)(base & (size_t)(N - 1));
  u16x8 y8 = *reinterpret_cast<const u16x8*>(&Y[base]);
  float4 o0, o1;
  o0.x = ((bf2f(y8[0]) - meanv[c0 + 0]) * Av[c0 + 0] + beta[c0 + 0] >= 2.0f) ? 1.f : 0.f;
  o0.y = ((bf2f(y8[1]) - meanv[c0 + 1]) * Av[c0 + 1] + beta[c0 + 1] >= 2.0f) ? 1.f : 0.f;
  o0.z = ((bf2f(y8[2]) - meanv[c0 + 2]) * Av[c0 + 2] + beta[c0 + 2] >= 2.0f) ? 1.f : 0.f;
  o0.w = ((bf2f(y8[3]) - meanv[c0 + 3]) * Av[c0 + 3] + beta[c0 + 3] >= 2.0f) ? 1.f : 0.f;
  o1.x = ((bf2f(y8[4]) - meanv[c0 + 4]) * Av[c0 + 4] + beta[c0 + 4] >= 2.0f) ? 1.f : 0.f;
  o1.y = ((bf2f(y8[5]) - meanv[c0 + 5]) * Av[c0 + 5] + beta[c0 + 5] >= 2.0f) ? 1.f : 0.f;
  o1.z = ((bf2f(y8[6]) - meanv[c0 + 6]) * Av[c0 + 6] + beta[c0 + 6] >= 2.0f) ? 1.f : 0.f;
  o1.w = ((bf2f(y8[7]) - meanv[c0 + 7]) * Av[c0 + 7] + beta[c0 + 7] >= 2.0f) ? 1.f : 0.f;
  *reinterpret_cast<float4*>(&S[base]) = o0;
  *reinterpret_cast<float4*>(&S[base + 4]) = o1;
}

// =============== gate: energy_int/1024 (exact) -> gate + any-flags ===============
__global__ void gate_kernel(const int* __restrict__ energy_int, const float* __restrict__ Wg,
                            const float* __restrict__ bg, float* __restrict__ gate,
                            int* __restrict__ flags, int D)
{
  int b = blockIdx.x >> 4, hp = blockIdx.x & 15;
  int tid = threadIdx.x;
  float e[16];
#pragma unroll
  for (int h = 0; h < 16; ++h) e[h] = (float)energy_int[b * 16 + h] * (1.f / 1024.f);
  float s = 0.f;
  for (int j = tid; j < D; j += 256) s = fmaf(e[j & 15], Wg[(size_t)hp * D + j], s);
  __shared__ float red[256];
  red[tid] = s;
  __syncthreads();
  for (int off = 128; off; off >>= 1) {
    if (tid < off) red[tid] += red[tid + off];
    __syncthreads();
  }
  if (tid == 0) {
    int gv = (red[0] + bg[hp] >= 0.5f) ? 1 : 0;
    gate[blockIdx.x] = (float)gv;
    if (gv) { atomicOr(&flags[0], 1); atomicOr(&flags[1 + b], 1); }
  }
}

// =============== gated attention + spike -> xat2 bf16 [4096][2048]=[s|s] ===============
__global__ __launch_bounds__(256) void attn_kernel(
    const unsigned short* __restrict__ qb, const unsigned short* __restrict__ kb,
    const unsigned short* __restrict__ vb, const float* __restrict__ gate,
    const int* __restrict__ flags, unsigned short* __restrict__ xs,
    int Ntok, int D, float scale)
{
  int bh = blockIdx.x;
  int b = bh >> 4, h = bh & 15;
  if (flags[1 + b] == 0) return;     // whole batch gated off -> p-GEMM skips it, xs unread
  int n0 = blockIdx.y * 32;
  int tid = threadIdx.x;
  unsigned short* outbase = xs + (size_t)(b * Ntok + n0) * 2048 + h * 64;

  if (gate[bh] == 0.f) {
    ushort4 zv = {0, 0, 0, 0};
    for (int i = tid; i < 32 * 16; i += 256) {
      int r = i >> 4, c4 = (i & 15) << 2;
      *reinterpret_cast<ushort4*>(&outbase[(size_t)r * 2048 + c4]) = zv;
      *reinterpret_cast<ushort4*>(&outbase[(size_t)r * 2048 + 1024 + c4]) = zv;
    }
    return;
  }

  __shared__ float qs[32][68], ks[32][68], vs[32][68], Ss[32][36];
  const unsigned short* qg = qb + (size_t)b * Ntok * D + h * 64;
  const unsigned short* kg = kb + (size_t)b * Ntok * D + h * 64;
  const unsigned short* vg = vb + (size_t)b * Ntok * D + h * 64;

  {
    int r = tid >> 3, c8 = (tid & 7) * 8;
    u16x8 t = *reinterpret_cast<const u16x8*>(&qg[(size_t)(n0 + r) * D + c8]);
#pragma unroll
    for (int e = 0; e < 8; ++e) qs[r][c8 + e] = bf2f(t[e]);
  }

  float acc[8];
#pragma unroll
  for (int j = 0; j < 8; ++j) acc[j] = 0.f;
  const int nloc = tid >> 3;
  const int dd0 = (tid & 7) * 8;

  for (int mt = 0; mt < Ntok / 32; ++mt) {
    int m0 = mt * 32;
    __syncthreads();
    {
      int r = tid >> 3, c8 = (tid & 7) * 8;
      u16x8 tk = *reinterpret_cast<const u16x8*>(&kg[(size_t)(m0 + r) * D + c8]);
      u16x8 tv = *reinterpret_cast<const u16x8*>(&vg[(size_t)(m0 + r) * D + c8]);
#pragma unroll
      for (int e = 0; e < 8; ++e) { ks[r][c8 + e] = bf2f(tk[e]); vs[r][c8 + e] = bf2f(tv[e]); }
    }
    __syncthreads();
    {
      int np = tid >> 3;
      int mp0 = (tid & 7) * 4;
      float s0 = 0.f, s1 = 0.f, s2 = 0.f, s3 = 0.f;
#pragma unroll 8
      for (int d = 0; d < 64; ++d) {
        float qv = qs[np][d];
        s0 = fmaf(qv, ks[mp0 + 0][d], s0);
        s1 = fmaf(qv, ks[mp0 + 1][d], s1);
        s2 = fmaf(qv, ks[mp0 + 2][d], s2);
        s3 = fmaf(qv, ks[mp0 + 3][d], s3);
      }
      Ss[np][mp0 + 0] = s0; Ss[np][mp0 + 1] = s1;
      Ss[np][mp0 + 2] = s2; Ss[np][mp0 + 3] = s3;
    }
    __syncthreads();
#pragma unroll 8
    for (int mp = 0; mp < 32; ++mp) {
      float sv = Ss[nloc][mp];
#pragma unroll
      for (int j = 0; j < 8; ++j) acc[j] = fmaf(sv, vs[mp][dd0 + j], acc[j]);
    }
  }

#pragma unroll
  for (int j = 0; j < 8; ++j) {
    float x = scale * acc[j];
    unsigned short sp = (x >= 1.0f) ? 0x3F80 : 0;
    outbase[(size_t)nloc * 2048 + dd0 + j] = sp;
    outbase[(size_t)nloc * 2048 + 1024 + dd0 + j] = sp;
  }
}

// ======================================================================
extern "C" void kernel_launch(void* const* d_in, const int* in_sizes, int n_in,
                              void* d_out, int out_size, void* d_ws, size_t ws_size,
                              hipStream_t stream)
{
  (void)in_sizes; (void)n_in; (void)out_size; (void)ws_size;
  const int Ntok = 1024, D = 1024;
  const int M = 4096;
  const float scale = 0.5946035575013605f;      // 64^(-1/8)

  const float* x     = (const float*)d_in[0];
  const float* Wq    = (const float*)d_in[1];
  const float* bq    = (const float*)d_in[2];
  const float* gq    = (const float*)d_in[3];
  const float* betaq = (const float*)d_in[4];
  const float* Wk    = (const float*)d_in[5];
  const float* bk    = (const float*)d_in[6];
  const float* gk    = (const float*)d_in[7];
  const float* betak = (const float*)d_in[8];
  const float* Wv    = (const float*)d_in[9];
  const float* bv    = (const float*)d_in[10];
  const float* gv    = (const float*)d_in[11];
  const float* betav = (const float*)d_in[12];
  const float* Wp    = (const float*)d_in[13];
  const float* bp    = (const float*)d_in[14];
  const float* gp    = (const float*)d_in[15];
  const float* betap = (const float*)d_in[16];
  const float* Wg    = (const float*)d_in[17];
  const float* bg    = (const float*)d_in[18];

  char* w = (char*)d_ws;
  const size_t MB = 1024 * 1024;
  const size_t MN = (size_t)M * D;
  unsigned short* Y3bf  = (unsigned short*)(w + 0 * MB);    // 24 MB: q,k,v pre-activations
  unsigned short* xat2  = (unsigned short*)(w + 0 * MB);    // alias 16 MB (q,k slots dead)
  unsigned short* Yv    = Y3bf + 2 * MN;                    // v slot (8 MB, survives alias)
  unsigned short* Yp    = (unsigned short*)(w + 24 * MB);   // 8 MB
  unsigned short* Wpcat = (unsigned short*)(w + 32 * MB);   // 4 MB
  unsigned short* Xh    = (unsigned short*)(w + 48 * MB);   // 8 MB
  unsigned short* Wh3   = (unsigned short*)(w + 56 * MB);   // 6 MB
  unsigned short* qb2   = (unsigned short*)(w + 62 * MB);   // 8 MB
  unsigned short* kb2   = (unsigned short*)(w + 70 * MB);   // 8 MB
  unsigned short* vb2   = (unsigned short*)(w + 78 * MB);   // 8 MB
  double* psum   = (double*)(w + 86 * MB);                  // 3*32*1024*8 = 768 KB
  double* psq    = (double*)(w + 87 * MB);                  // 768 KB
  float*  meanv  = (float*)(w + 88 * MB);                   // 3 KB slots
  float*  Av     = (float*)(w + 88 * MB + 16384);
  int*    energy_int = (int*)(w + 88 * MB + 32768);         // 64 ints
  int*    flags  = (int*)(w + 88 * MB + 32768 + 512);       // [any, batch0..3]
  float*  gate   = (float*)(w + 88 * MB + 32768 + 1024);    // 64 floats

  float* out = (float*)d_out;
  unsigned short* Whq = Wh3;
  unsigned short* Whk = Wh3 + MN / 4;       // 1024*1024
  unsigned short* Whv = Wh3 + MN / 2;

  // ---- converts (single kernel) ----
  prep_kernel<<<dim3(4096), 256, 0, stream>>>(x, Wq, Wk, Wv, Wp, Xh, Wh3, Wpcat);

  // ---- q,k GEMM (+fused stats) ----
  gemm_bf16_bt<0><<<dim3(8, 32, 2), 256, 0, stream>>>(
      Xh, Whq, Whk, bq, bk, Y3bf, psum, psq, nullptr, D, 1024);
  bn_finalize<<<dim3(4, 2), 256, 0, stream>>>(
      psum, psq, gq, gk, meanv, Av, nullptr, flags, energy_int, D, 1.0 / M);
  spike_qk_energy<<<dim3(512), 256, 0, stream>>>(
      Y3bf, Y3bf + MN, meanv, Av, betaq, betak, qb2, kb2, energy_int, D);

  // ---- gate ----
  gate_kernel<<<dim3(64), 256, 0, stream>>>(energy_int, Wg, bg, gate, flags, D);

  // ---- v branch (fully skipped when no gate fires) ----
  gemm_bf16_bt<2><<<dim3(8, 32, 1), 256, 0, stream>>>(
      Xh, Whv, Whv, bv, bv, Yv, psum + 2 * 32 * (size_t)D, psq + 2 * 32 * (size_t)D,
      flags, D, 1024);
  bn_finalize<<<dim3(4, 1), 256, 0, stream>>>(
      psum + 2 * 32 * (size_t)D, psq + 2 * 32 * (size_t)D, gv, gv,
      meanv + 2 * D, Av + 2 * D, flags, nullptr, nullptr, D, 1.0 / M);
  spike_v<<<dim3(2048), 256, 0, stream>>>(Yv, meanv + 2 * D, Av + 2 * D, betav, vb2, flags, D);

  // ---- gated attention + spike -> xat2 ([s|s] bf16) ----
  attn_kernel<<<dim3(64, Ntok / 32), 256, 0, stream>>>(
      qb2, kb2, vb2, gate, flags, xat2, Ntok, D, scale);

  // ---- p branch: A=[s|s], B=[Wp_hi|Wp_lo], K=2048; per-batch skip ----
  gemm_bf16_bt<1><<<dim3(8, 32, 1), 256, 0, stream>>>(
      xat2, Wpcat, Wpcat, bp, bp, Yp, psum, psq, flags, D, 2048);
  bn_finalize<<<dim3(4, 1), 256, 0, stream>>>(
      psum, psq, gp, gp, meanv, Av, nullptr, nullptr, nullptr, D, 1.0 / M);
  bn_spike_f32<<<dim3(2048), 256, 0, stream>>>(Yp, meanv, Av, betap, out, D);
}

// Round 7
// 75.269 us; speedup vs baseline: 14.3038x; 1.0495x over previous
//
#include <hip/hip_runtime.h>
#include <cstddef>
#include <cstdint>

#define EPS 1e-5f

typedef __bf16 bf16x8 __attribute__((ext_vector_type(8)));
typedef float f32x4 __attribute__((ext_vector_type(4)));
typedef unsigned short u16x8 __attribute__((ext_vector_type(8)));

__device__ __forceinline__ unsigned short f2bf(float f) {
  unsigned u = __builtin_bit_cast(unsigned, f);
  unsigned r = u + 0x7FFFu + ((u >> 16) & 1u);
  return (unsigned short)(r >> 16);
}
__device__ __forceinline__ float bf2f(unsigned short h) {
  unsigned u = (unsigned)h << 16;
  return __builtin_bit_cast(float, u);
}

__device__ __forceinline__ void gl_lds16(const void* g, void* l) {
  __builtin_amdgcn_global_load_lds(
      (const __attribute__((address_space(1))) unsigned int*)g,
      (__attribute__((address_space(3))) unsigned int*)l, 16, 0, 0);
}

// =============== bf16 MFMA GEMM: dbuf + COUNTED vmcnt (prefetch never drained) ===============
// MODE 0: plain (z selects W0/W1 via grid.z)
// MODE 1: per-batch skip of K-loop (p-branch; epilogue still writes bias + stats)
// MODE 2: full kernel skip when flags[0]==0 (v-branch; outputs unread in that case)
template <int MODE>
__global__ __launch_bounds__(256) void gemm_bf16_bt(
    const unsigned short* __restrict__ A,
    const unsigned short* __restrict__ W0, const unsigned short* __restrict__ W1,
    const float* __restrict__ b0, const float* __restrict__ b1,
    unsigned short* __restrict__ Y, double* __restrict__ psum, double* __restrict__ psq,
    const int* __restrict__ flags, int N, int Kc)
{
  if (MODE == 2) { if (flags[0] == 0) return; }

  __shared__ unsigned short As[2][8192];   // 2 x 16 KB
  __shared__ unsigned short Bs[2][8192];   // 2 x 16 KB
  const int tid = threadIdx.x;

  // XCD-chunked swizzle
  const int bid = blockIdx.x + (blockIdx.y << 3) + (blockIdx.z << 8);
  const int nwg = (int)gridDim.z << 8;
  const int cpx = nwg >> 3;
  const int sw = (bid & 7) * cpx + (bid >> 3);
  const int bx = sw & 7, by = (sw >> 3) & 31, z = sw >> 8;

  const unsigned short* Bm = z ? W1 : W0;
  const float* bias = z ? b1 : b0;
  unsigned short* Yz = Y + (size_t)z * 4096 * N;

  const int bm = by * 128, bn = bx * 128;
  const int lane = tid & 63, w = tid >> 6;
  const int wr = w >> 1, wc = w & 1;            // wave tile 64x64
  const int l15 = lane & 15, g = lane >> 4;

  f32x4 acc[4][4] = {};

  bool skip = false;
  if (MODE == 1) skip = (flags[1 + (by >> 3)] == 0);

  if (!skip) {
    const unsigned short* aSrc[4]; const unsigned short* bSrc[4]; int dOff[4];
#pragma unroll
    for (int c = 0; c < 4; ++c) {
      int S = c * 256 + tid;
      int row = S >> 3, sp = S & 7;
      int sl = sp ^ (row & 7);
      aSrc[c] = A  + (size_t)(bm + row) * Kc + sl * 8;
      bSrc[c] = Bm + (size_t)(bn + row) * Kc + sl * 8;
      dOff[c] = S * 8;
    }
    int aOff[4][2], bOff[4][2];
#pragma unroll
    for (int i = 0; i < 4; ++i)
#pragma unroll
      for (int t = 0; t < 2; ++t) {
        int rowA = wr * 64 + i * 16 + l15;
        aOff[i][t] = rowA * 64 + ((t * 4 + g) ^ (rowA & 7)) * 8;
        int rowB = wc * 64 + i * 16 + l15;
        bOff[i][t] = rowB * 64 + ((t * 4 + g) ^ (rowB & 7)) * 8;
      }

    const int nk = Kc >> 6;
    // prologue: stage tile 0 into buf 0 (8 gl_lds per wave)
#pragma unroll
    for (int c = 0; c < 4; ++c) { gl_lds16(aSrc[c], &As[0][dOff[c]]); aSrc[c] += 64; }
#pragma unroll
    for (int c = 0; c < 4; ++c) { gl_lds16(bSrc[c], &Bs[0][dOff[c]]); bSrc[c] += 64; }

    int cur = 0;
    for (int kt = 0; kt < nk; ++kt) {
      if (kt + 1 < nk) {
        // issue next-tile stage; keep it IN FLIGHT across the barriers
#pragma unroll
        for (int c = 0; c < 4; ++c) { gl_lds16(aSrc[c], &As[cur ^ 1][dOff[c]]); aSrc[c] += 64; }
#pragma unroll
        for (int c = 0; c < 4; ++c) { gl_lds16(bSrc[c], &Bs[cur ^ 1][dOff[c]]); bSrc[c] += 64; }
        asm volatile("s_waitcnt vmcnt(8)" ::: "memory");   // tile kt landed (8 newest allowed out)
      } else {
        asm volatile("s_waitcnt vmcnt(0)" ::: "memory");   // last tile: full drain
      }
      __builtin_amdgcn_s_barrier();
      __builtin_amdgcn_sched_barrier(0);
      {
        const unsigned short* Ac = &As[cur][0];
        const unsigned short* Bc = &Bs[cur][0];
#pragma unroll
        for (int t = 0; t < 2; ++t) {
          bf16x8 af[4], bfr[4];
#pragma unroll
          for (int i = 0; i < 4; ++i) af[i] = *(const bf16x8*)&Ac[aOff[i][t]];
#pragma unroll
          for (int j = 0; j < 4; ++j) bfr[j] = *(const bf16x8*)&Bc[bOff[j][t]];
#pragma unroll
          for (int i = 0; i < 4; ++i)
#pragma unroll
            for (int j = 0; j < 4; ++j)
              acc[i][j] = __builtin_amdgcn_mfma_f32_16x16x32_bf16(af[i], bfr[j], acc[i][j], 0, 0, 0);
        }
      }
      __builtin_amdgcn_s_barrier();   // readers done; buf[cur] safe to overwrite next iter
      cur ^= 1;
    }
  }

  // ---- epilogue: bf16 store + per-column partials (of stored values) ----
  const int r0 = bm + wr * 64 + g * 4;
  float csum[4], csq[4];
#pragma unroll
  for (int j = 0; j < 4; ++j) { csum[j] = 0.f; csq[j] = 0.f; }
#pragma unroll
  for (int j = 0; j < 4; ++j) {
    int col = bn + wc * 64 + j * 16 + l15;
    float bv = bias[col];
#pragma unroll
    for (int i = 0; i < 4; ++i)
#pragma unroll
      for (int r = 0; r < 4; ++r) {
        float yv = acc[i][j][r] + bv;
        unsigned short h = f2bf(yv);
        float yb = bf2f(h);
        Yz[(size_t)(r0 + i * 16 + r) * N + col] = h;
        csum[j] += yb;
        csq[j] += yb * yb;
      }
  }
  __syncthreads();
  float* Ls = (float*)&As[0][0];                 // 8 slots x 128 cols, sums then sqs
  const int slot = wr * 4 + g;
#pragma unroll
  for (int j = 0; j < 4; ++j) {
    int ci = wc * 64 + j * 16 + l15;
    Ls[slot * 128 + ci] = csum[j];
    Ls[1024 + slot * 128 + ci] = csq[j];
  }
  __syncthreads();
  if (tid < 128) {
    double s = 0.0, q = 0.0;
#pragma unroll
    for (int sl = 0; sl < 8; ++sl) {
      s += (double)Ls[sl * 128 + tid];
      q += (double)Ls[1024 + sl * 128 + tid];
    }
    size_t o = ((size_t)z * 32 + by) * N + bn + tid;
    psum[o] = s;
    psq[o] = q;
  }
}

// =============== prep1: x, Wq, Wk converts (always needed) ===============
// blocks 0..2047: x -> Xh ; 2048..2559: Wq ; 2560..3071: Wk
__global__ void prep1_kernel(const float* __restrict__ x,
                             const float* __restrict__ Wq, const float* __restrict__ Wk,
                             unsigned short* __restrict__ Xh, unsigned short* __restrict__ Wh3)
{
  int bid = blockIdx.x, tid = threadIdx.x;
  const float* src; unsigned short* dst; size_t base;
  if (bid < 2048) {
    src = x; dst = Xh; base = ((size_t)bid * 256 + tid) * 8;
  } else if (bid < 2560) {
    src = Wq; dst = Wh3; base = ((size_t)(bid - 2048) * 256 + tid) * 8;
  } else {
    src = Wk; dst = Wh3 + (size_t)1024 * 1024; base = ((size_t)(bid - 2560) * 256 + tid) * 8;
  }
  float4 a = *reinterpret_cast<const float4*>(&src[base]);
  float4 b = *reinterpret_cast<const float4*>(&src[base + 4]);
  u16x8 o;
  o[0] = f2bf(a.x); o[1] = f2bf(a.y); o[2] = f2bf(a.z); o[3] = f2bf(a.w);
  o[4] = f2bf(b.x); o[5] = f2bf(b.y); o[6] = f2bf(b.z); o[7] = f2bf(b.w);
  *reinterpret_cast<u16x8*>(&dst[base]) = o;
}

// =============== prep2: Wv convert + Wp [hi|lo] split — only if some gate fired ===============
// blocks 0..511: Wv -> Whv ; 512..1023: Wp -> Wpcat
__global__ void prep2_kernel(const float* __restrict__ Wv, const float* __restrict__ Wp,
                             unsigned short* __restrict__ Whv, unsigned short* __restrict__ Wpcat,
                             const int* __restrict__ flags)
{
  if (flags[0] == 0) return;
  int bid = blockIdx.x, tid = threadIdx.x;
  if (bid < 512) {
    size_t base = ((size_t)bid * 256 + tid) * 8;
    float4 a = *reinterpret_cast<const float4*>(&Wv[base]);
    float4 b = *reinterpret_cast<const float4*>(&Wv[base + 4]);
    u16x8 o;
    o[0] = f2bf(a.x); o[1] = f2bf(a.y); o[2] = f2bf(a.z); o[3] = f2bf(a.w);
    o[4] = f2bf(b.x); o[5] = f2bf(b.y); o[6] = f2bf(b.z); o[7] = f2bf(b.w);
    *reinterpret_cast<u16x8*>(&Whv[base]) = o;
  } else {
    size_t base = ((size_t)(bid - 512) * 256 + tid) * 8;
    int r = (int)(base >> 10), c = (int)(base & 1023);
    float4 a = *reinterpret_cast<const float4*>(&Wp[base]);
    float4 b = *reinterpret_cast<const float4*>(&Wp[base + 4]);
    u16x8 hi, lo;
    hi[0] = f2bf(a.x); lo[0] = f2bf(a.x - bf2f(hi[0]));
    hi[1] = f2bf(a.y); lo[1] = f2bf(a.y - bf2f(hi[1]));
    hi[2] = f2bf(a.z); lo[2] = f2bf(a.z - bf2f(hi[2]));
    hi[3] = f2bf(a.w); lo[3] = f2bf(a.w - bf2f(hi[3]));
    hi[4] = f2bf(b.x); lo[4] = f2bf(b.x - bf2f(hi[4]));
    hi[5] = f2bf(b.y); lo[5] = f2bf(b.y - bf2f(hi[5]));
    hi[6] = f2bf(b.z); lo[6] = f2bf(b.z - bf2f(hi[6]));
    hi[7] = f2bf(b.w); lo[7] = f2bf(b.w - bf2f(hi[7]));
    unsigned short* Or = Wpcat + (size_t)r * 2048;
    *reinterpret_cast<u16x8*>(&Or[c]) = hi;
    *reinterpret_cast<u16x8*>(&Or[1024 + c]) = lo;
  }
}

// =============== BN finalize (32 partial blocks), fully unrolled ===============
__global__ void bn_finalize(const double* __restrict__ psum, const double* __restrict__ psq,
                            const float* __restrict__ g0, const float* __restrict__ g1,
                            float* __restrict__ meanv, float* __restrict__ Av,
                            const int* __restrict__ runflag,
                            int* __restrict__ zflags, int* __restrict__ zenergy,
                            int N, double invM)
{
  if (zflags && blockIdx.x == 0 && blockIdx.y == 0) {
    int t = threadIdx.x;
    if (t < 5) zflags[t] = 0;
    if (t >= 64 && t < 128) zenergy[t - 64] = 0;
  }
  if (runflag && runflag[0] == 0) return;
  int z = blockIdx.y;
  const float* g = z ? g1 : g0;
  int c = blockIdx.x * blockDim.x + threadIdx.x;
  const double* ps = psum + (size_t)z * 32 * N + c;
  const double* pq = psq  + (size_t)z * 32 * N + c;
  double s0 = 0, s1 = 0, q0 = 0, q1 = 0;
#pragma unroll
  for (int rb = 0; rb < 32; rb += 2) {
    s0 += ps[(size_t)rb * N];       q0 += pq[(size_t)rb * N];
    s1 += ps[(size_t)(rb + 1) * N]; q1 += pq[(size_t)(rb + 1) * N];
  }
  double s = s0 + s1, q = q0 + q1;
  double m = s * invM;
  double var = q * invM - m * m;
  if (var < 0.0) var = 0.0;
  meanv[(size_t)z * N + c] = (float)m;
  Av[(size_t)z * N + c] = g[(size_t)c] * rsqrtf((float)var + EPS);
}

// =============== q/k spike + fused energy popcount (deterministic int atomics) ===============
__global__ void spike_qk_energy(const unsigned short* __restrict__ Yq,
                                const unsigned short* __restrict__ Yk,
                                const float* __restrict__ meanv, const float* __restrict__ Av,
                                const float* __restrict__ beq, const float* __restrict__ bek,
                                unsigned short* __restrict__ qb, unsigned short* __restrict__ kb,
                                int* __restrict__ energy_int, int N)
{
  const int tid = threadIdx.x;
  const int c0 = (tid * 8) & (N - 1);
  const int head = c0 >> 6;
  const int batch = blockIdx.x >> 7;
  const float* mq = meanv;            const float* aq = Av;
  const float* mk = meanv + N;        const float* ak = Av + N;
  __shared__ int bins[16];
  if (tid < 16) bins[tid] = 0;
  __syncthreads();
  int cnt = 0;
#pragma unroll
  for (int j = 0; j < 4; ++j) {
    size_t base = (size_t)blockIdx.x * 8192 + j * 2048 + tid * 8;
    u16x8 yq = *reinterpret_cast<const u16x8*>(&Yq[base]);
    u16x8 yk = *reinterpret_cast<const u16x8*>(&Yk[base]);
    u16x8 oq, ok;
#pragma unroll
    for (int e = 0; e < 8; ++e) {
      bool sq = (bf2f(yq[e]) - mq[c0 + e]) * aq[c0 + e] + beq[c0 + e] >= 2.0f;
      bool sk = (bf2f(yk[e]) - mk[c0 + e]) * ak[c0 + e] + bek[c0 + e] >= 2.0f;
      oq[e] = sq ? 0x3F80 : 0;
      ok[e] = sk ? 0x3F80 : 0;
      cnt += (sq && sk) ? 1 : 0;
    }
    *reinterpret_cast<u16x8*>(&qb[base]) = oq;
    *reinterpret_cast<u16x8*>(&kb[base]) = ok;
  }
  atomicAdd(&bins[head], cnt);
  __syncthreads();
  if (tid < 16) atomicAdd(&energy_int[batch * 16 + tid], bins[tid]);
}

// =============== v spike (flag-guarded) ===============
__global__ void spike_v(const unsigned short* __restrict__ Yv,
                        const float* __restrict__ meanv, const float* __restrict__ Av,
                        const float* __restrict__ beta, unsigned short* __restrict__ vb,
                        const int* __restrict__ flags, int N)
{
  if (flags[0] == 0) return;
  size_t base = ((size_t)blockIdx.x * 256 + threadIdx.x) * 8;
  int c0 = (int)(base & (size_t)(N - 1));
  u16x8 y8 = *reinterpret_cast<const u16x8*>(&Yv[base]);
  u16x8 o;
#pragma unroll
  for (int e = 0; e < 8; ++e)
    o[e] = ((bf2f(y8[e]) - meanv[c0 + e]) * Av[c0 + e] + beta[c0 + e] >= 2.0f) ? 0x3F80 : 0;
  *reinterpret_cast<u16x8*>(&vb[base]) = o;
}

// =============== final output spike ===============
__global__ void bn_spike_f32(const unsigned short* __restrict__ Y,
                             const float* __restrict__ meanv, const float* __restrict__ Av,
                             const float* __restrict__ beta, float* __restrict__ S, int N)
{
  size_t base = ((size_t)blockIdx.x * 256 + threadIdx.x) * 8;
  int c0 = (int)(base & (size_t)(N - 1));
  u16x8 y8 = *reinterpret_cast<const u16x8*>(&Y[base]);
  float4 o0, o1;
  o0.x = ((bf2f(y8[0]) - meanv[c0 + 0]) * Av[c0 + 0] + beta[c0 + 0] >= 2.0f) ? 1.f : 0.f;
  o0.y = ((bf2f(y8[1]) - meanv[c0 + 1]) * Av[c0 + 1] + beta[c0 + 1] >= 2.0f) ? 1.f : 0.f;
  o0.z = ((bf2f(y8[2]) - meanv[c0 + 2]) * Av[c0 + 2] + beta[c0 + 2] >= 2.0f) ? 1.f : 0.f;
  o0.w = ((bf2f(y8[3]) - meanv[c0 + 3]) * Av[c0 + 3] + beta[c0 + 3] >= 2.0f) ? 1.f : 0.f;
  o1.x = ((bf2f(y8[4]) - meanv[c0 + 4]) * Av[c0 + 4] + beta[c0 + 4] >= 2.0f) ? 1.f : 0.f;
  o1.y = ((bf2f(y8[5]) - meanv[c0 + 5]) * Av[c0 + 5] + beta[c0 + 5] >= 2.0f) ? 1.f : 0.f;
  o1.z = ((bf2f(y8[6]) - meanv[c0 + 6]) * Av[c0 + 6] + beta[c0 + 6] >= 2.0f) ? 1.f : 0.f;
  o1.w = ((bf2f(y8[7]) - meanv[c0 + 7]) * Av[c0 + 7] + beta[c0 + 7] >= 2.0f) ? 1.f : 0.f;
  *reinterpret_cast<float4*>(&S[base]) = o0;
  *reinterpret_cast<float4*>(&S[base + 4]) = o1;
}

// =============== gate: energy_int/1024 (exact) -> gate + any-flags ===============
__global__ void gate_kernel(const int* __restrict__ energy_int, const float* __restrict__ Wg,
                            const float* __restrict__ bg, float* __restrict__ gate,
                            int* __restrict__ flags, int D)
{
  int b = blockIdx.x >> 4, hp = blockIdx.x & 15;
  int tid = threadIdx.x;
  float e[16];
#pragma unroll
  for (int h = 0; h < 16; ++h) e[h] = (float)energy_int[b * 16 + h] * (1.f / 1024.f);
  float s = 0.f;
  for (int j = tid; j < D; j += 256) s = fmaf(e[j & 15], Wg[(size_t)hp * D + j], s);
  __shared__ float red[256];
  red[tid] = s;
  __syncthreads();
  for (int off = 128; off; off >>= 1) {
    if (tid < off) red[tid] += red[tid + off];
    __syncthreads();
  }
  if (tid == 0) {
    int gv = (red[0] + bg[hp] >= 0.5f) ? 1 : 0;
    gate[blockIdx.x] = (float)gv;
    if (gv) { atomicOr(&flags[0], 1); atomicOr(&flags[1 + b], 1); }
  }
}

// =============== gated attention + spike -> xat2 bf16 [4096][2048]=[s|s] ===============
__global__ __launch_bounds__(256) void attn_kernel(
    const unsigned short* __restrict__ qb, const unsigned short* __restrict__ kb,
    const unsigned short* __restrict__ vb, const float* __restrict__ gate,
    const int* __restrict__ flags, unsigned short* __restrict__ xs,
    int Ntok, int D, float scale)
{
  int bh = blockIdx.x;
  int b = bh >> 4, h = bh & 15;
  if (flags[1 + b] == 0) return;     // whole batch gated off -> p-GEMM skips it, xs unread
  int n0 = blockIdx.y * 32;
  int tid = threadIdx.x;
  unsigned short* outbase = xs + (size_t)(b * Ntok + n0) * 2048 + h * 64;

  if (gate[bh] == 0.f) {
    ushort4 zv = {0, 0, 0, 0};
    for (int i = tid; i < 32 * 16; i += 256) {
      int r = i >> 4, c4 = (i & 15) << 2;
      *reinterpret_cast<ushort4*>(&outbase[(size_t)r * 2048 + c4]) = zv;
      *reinterpret_cast<ushort4*>(&outbase[(size_t)r * 2048 + 1024 + c4]) = zv;
    }
    return;
  }

  __shared__ float qs[32][68], ks[32][68], vs[32][68], Ss[32][36];
  const unsigned short* qg = qb + (size_t)b * Ntok * D + h * 64;
  const unsigned short* kg = kb + (size_t)b * Ntok * D + h * 64;
  const unsigned short* vg = vb + (size_t)b * Ntok * D + h * 64;

  {
    int r = tid >> 3, c8 = (tid & 7) * 8;
    u16x8 t = *reinterpret_cast<const u16x8*>(&qg[(size_t)(n0 + r) * D + c8]);
#pragma unroll
    for (int e = 0; e < 8; ++e) qs[r][c8 + e] = bf2f(t[e]);
  }

  float acc[8];
#pragma unroll
  for (int j = 0; j < 8; ++j) acc[j] = 0.f;
  const int nloc = tid >> 3;
  const int dd0 = (tid & 7) * 8;

  for (int mt = 0; mt < Ntok / 32; ++mt) {
    int m0 = mt * 32;
    __syncthreads();
    {
      int r = tid >> 3, c8 = (tid & 7) * 8;
      u16x8 tk = *reinterpret_cast<const u16x8*>(&kg[(size_t)(m0 + r) * D + c8]);
      u16x8 tv = *reinterpret_cast<const u16x8*>(&vg[(size_t)(m0 + r) * D + c8]);
#pragma unroll
      for (int e = 0; e < 8; ++e) { ks[r][c8 + e] = bf2f(tk[e]); vs[r][c8 + e] = bf2f(tv[e]); }
    }
    __syncthreads();
    {
      int np = tid >> 3;
      int mp0 = (tid & 7) * 4;
      float s0 = 0.f, s1 = 0.f, s2 = 0.f, s3 = 0.f;
#pragma unroll 8
      for (int d = 0; d < 64; ++d) {
        float qv = qs[np][d];
        s0 = fmaf(qv, ks[mp0 + 0][d], s0);
        s1 = fmaf(qv, ks[mp0 + 1][d], s1);
        s2 = fmaf(qv, ks[mp0 + 2][d], s2);
        s3 = fmaf(qv, ks[mp0 + 3][d], s3);
      }
      Ss[np][mp0 + 0] = s0; Ss[np][mp0 + 1] = s1;
      Ss[np][mp0 + 2] = s2; Ss[np][mp0 + 3] = s3;
    }
    __syncthreads();
#pragma unroll 8
    for (int mp = 0; mp < 32; ++mp) {
      float sv = Ss[nloc][mp];
#pragma unroll
      for (int j = 0; j < 8; ++j) acc[j] = fmaf(sv, vs[mp][dd0 + j], acc[j]);
    }
  }

#pragma unroll
  for (int j = 0; j < 8; ++j) {
    float x = scale * acc[j];
    unsigned short sp = (x >= 1.0f) ? 0x3F80 : 0;
    outbase[(size_t)nloc * 2048 + dd0 + j] = sp;
    outbase[(size_t)nloc * 2048 + 1024 + dd0 + j] = sp;
  }
}

// ======================================================================
extern "C" void kernel_launch(void* const* d_in, const int* in_sizes, int n_in,
                              void* d_out, int out_size, void* d_ws, size_t ws_size,
                              hipStream_t stream)
{
  (void)in_sizes; (void)n_in; (void)out_size; (void)ws_size;
  const int Ntok = 1024, D = 1024;
  const int M = 4096;
  const float scale = 0.5946035575013605f;      // 64^(-1/8)

  const float* x     = (const float*)d_in[0];
  const float* Wq    = (const float*)d_in[1];
  const float* bq    = (const float*)d_in[2];
  const float* gq    = (const float*)d_in[3];
  const float* betaq = (const float*)d_in[4];
  const float* Wk    = (const float*)d_in[5];
  const float* bk    = (const float*)d_in[6];
  const float* gk    = (const float*)d_in[7];
  const float* betak = (const float*)d_in[8];
  const float* Wv    = (const float*)d_in[9];
  const float* bv    = (const float*)d_in[10];
  const float* gv    = (const float*)d_in[11];
  const float* betav = (const float*)d_in[12];
  const float* Wp    = (const float*)d_in[13];
  const float* bp    = (const float*)d_in[14];
  const float* gp    = (const float*)d_in[15];
  const float* betap = (const float*)d_in[16];
  const float* Wg    = (const float*)d_in[17];
  const float* bg    = (const float*)d_in[18];

  char* w = (char*)d_ws;
  const size_t MB = 1024 * 1024;
  const size_t MN = (size_t)M * D;
  unsigned short* Y3bf  = (unsigned short*)(w + 0 * MB);    // 24 MB: q,k,v pre-activations
  unsigned short* xat2  = (unsigned short*)(w + 0 * MB);    // alias 16 MB (q,k slots dead)
  unsigned short* Yv    = Y3bf + 2 * MN;                    // v slot (8 MB, survives alias)
  unsigned short* Yp    = (unsigned short*)(w + 24 * MB);   // 8 MB
  unsigned short* Wpcat = (unsigned short*)(w + 32 * MB);   // 4 MB
  unsigned short* Xh    = (unsigned short*)(w + 48 * MB);   // 8 MB
  unsigned short* Wh3   = (unsigned short*)(w + 56 * MB);   // 6 MB
  unsigned short* qb2   = (unsigned short*)(w + 62 * MB);   // 8 MB
  unsigned short* kb2   = (unsigned short*)(w + 70 * MB);   // 8 MB
  unsigned short* vb2   = (unsigned short*)(w + 78 * MB);   // 8 MB
  double* psum   = (double*)(w + 86 * MB);                  // 768 KB
  double* psq    = (double*)(w + 87 * MB);                  // 768 KB
  float*  meanv  = (float*)(w + 88 * MB);
  float*  Av     = (float*)(w + 88 * MB + 16384);
  int*    energy_int = (int*)(w + 88 * MB + 32768);         // 64 ints
  int*    flags  = (int*)(w + 88 * MB + 32768 + 512);       // [any, batch0..3]
  float*  gate   = (float*)(w + 88 * MB + 32768 + 1024);    // 64 floats

  float* out = (float*)d_out;
  unsigned short* Whq = Wh3;
  unsigned short* Whk = Wh3 + MN / 4;       // 1024*1024
  unsigned short* Whv = Wh3 + MN / 2;

  // ---- converts (always-needed part) ----
  prep1_kernel<<<dim3(3072), 256, 0, stream>>>(x, Wq, Wk, Xh, Wh3);

  // ---- q,k GEMM (+fused stats) ----
  gemm_bf16_bt<0><<<dim3(8, 32, 2), 256, 0, stream>>>(
      Xh, Whq, Whk, bq, bk, Y3bf, psum, psq, nullptr, D, 1024);
  bn_finalize<<<dim3(4, 2), 256, 0, stream>>>(
      psum, psq, gq, gk, meanv, Av, nullptr, flags, energy_int, D, 1.0 / M);
  spike_qk_energy<<<dim3(512), 256, 0, stream>>>(
      Y3bf, Y3bf + MN, meanv, Av, betaq, betak, qb2, kb2, energy_int, D);

  // ---- gate ----
  gate_kernel<<<dim3(64), 256, 0, stream>>>(energy_int, Wg, bg, gate, flags, D);

  // ---- deferred converts (only if some gate fired) ----
  prep2_kernel<<<dim3(1024), 256, 0, stream>>>(Wv, Wp, Whv, Wpcat, flags);

  // ---- v branch (fully skipped when no gate fires) ----
  gemm_bf16_bt<2><<<dim3(8, 32, 1), 256, 0, stream>>>(
      Xh, Whv, Whv, bv, bv, Yv, psum + 2 * 32 * (size_t)D, psq + 2 * 32 * (size_t)D,
      flags, D, 1024);
  bn_finalize<<<dim3(4, 1), 256, 0, stream>>>(
      psum + 2 * 32 * (size_t)D, psq + 2 * 32 * (size_t)D, gv, gv,
      meanv + 2 * D, Av + 2 * D, flags, nullptr, nullptr, D, 1.0 / M);
  spike_v<<<dim3(2048), 256, 0, stream>>>(Yv, meanv + 2 * D, Av + 2 * D, betav, vb2, flags, D);

  // ---- gated attention + spike -> xat2 ([s|s] bf16) ----
  attn_kernel<<<dim3(64, Ntok / 32), 256, 0, stream>>>(
      qb2, kb2, vb2, gate, flags, xat2, Ntok, D, scale);

  // ---- p branch: A=[s|s], B=[Wp_hi|Wp_lo], K=2048; per-batch skip ----
  gemm_bf16_bt<1><<<dim3(8, 32, 1), 256, 0, stream>>>(
      xat2, Wpcat, Wpcat, bp, bp, Yp, psum, psq, flags, D, 2048);
  bn_finalize<<<dim3(4, 1), 256, 0, stream>>>(
      psum, psq, gp, gp, meanv, Av, nullptr, nullptr, nullptr, D, 1.0 / M);
  bn_spike_f32<<<dim3(2048), 256, 0, stream>>>(Yp, meanv, Av, betap, out, D);
}